// Round 9
// baseline (203.274 us; speedup 1.0000x reference)
//
#include <hip/hip_runtime.h>

#define N_TOK 4096
#define BATCH 4

typedef __attribute__((ext_vector_type(8))) short short8;
typedef __attribute__((ext_vector_type(4))) float floatx4;

// Pack two floats to packed bf16 pair (round-half-away): 3 VALU ops.
__device__ __forceinline__ unsigned pack_rnd(float a, float b) {
    unsigned ra = __float_as_uint(a) + 0x8000u;
    unsigned rb = __float_as_uint(b) + 0x8000u;
    return __builtin_amdgcn_perm(rb, ra, 0x07060302u);
}

// Split two floats into bf16 hi-pair and lo-pair.
__device__ __forceinline__ void split_pack(float a, float b,
                                           unsigned &ph, unsigned &pl) {
    unsigned ra = __float_as_uint(a) + 0x8000u;
    unsigned rb = __float_as_uint(b) + 0x8000u;
    ph = __builtin_amdgcn_perm(rb, ra, 0x07060302u);
    float la = a - __uint_as_float(ra & 0xffff0000u);
    float lb = b - __uint_as_float(rb & 0xffff0000u);
    pl = __builtin_amdgcn_perm(__float_as_uint(lb) + 0x8000u,
                               __float_as_uint(la) + 0x8000u, 0x07060302u);
}

__device__ __forceinline__ short8 mk_short8(unsigned p0, unsigned p1,
                                            unsigned p2, unsigned p3) {
    union { unsigned u[4]; short8 s; } c;
    c.u[0] = p0; c.u[1] = p1; c.u[2] = p2; c.u[3] = p3;
    return c.s;
}

// Convert 8 consecutive fp32 (two float4) into hi/lo short8 fragments.
__device__ __forceinline__ void cvt_frag(const float* src,
                                         short8 &hi, short8 &lo) {
    float4 w0 = *(const float4*)src;
    float4 w1 = *(const float4*)(src + 4);
    unsigned ph[4], pl[4];
    split_pack(w0.x, w0.y, ph[0], pl[0]);
    split_pack(w0.z, w0.w, ph[1], pl[1]);
    split_pack(w1.x, w1.y, ph[2], pl[2]);
    split_pack(w1.z, w1.w, ph[3], pl[3]);
    hi = mk_short8(ph[0], ph[1], ph[2], ph[3]);
    lo = mk_short8(pl[0], pl[1], pl[2], pl[3]);
}

__device__ __forceinline__ float fast_exp2(float x) {
#if __has_builtin(__builtin_amdgcn_exp2f)
    return __builtin_amdgcn_exp2f(x);
#else
    return exp2f(x);
#endif
}

// ---------------------------------------------------------------------------
// QKV GEMM, region-merged: grid (64 n, 3 region, 4 b) = 768 blocks (was
// 1536).  Each block computes a FULL 128-row region x 64 n tile: per 32-k
// chunk the x tile is staged ONCE (was 2x across the old m-blocks -- 6x
// per region-pair total) and both 64-row W sub-tiles are staged; B
// fragments are ds_read once and reused for both subs (24 MFMA/wave/kc).
// x global reads + x staging VALU/LDS halve.  Per-output accumulation
// order identical to round 6 -> absmax must be 3.051758e-05.
// LDS 30720 B.  256 threads.
// ---------------------------------------------------------------------------
__global__ __launch_bounds__(256) void gemm1_fused(
    const float* __restrict__ wq, const float* __restrict__ x,
    unsigned short* __restrict__ Qp, unsigned short* __restrict__ Kp,
    unsigned short* __restrict__ Vp)
{
    const int N = N_TOK;
    const int b = blockIdx.z;
    const int region = blockIdx.y;            // 0=Q, 1=K, 2=V
    const int col0 = blockIdx.x * 64;
    const int t = threadIdx.x;
    const int wave = t >> 6, lane = t & 63;
    const int l16 = lane & 15, quad = lane >> 4;
    const int msub0 = (wave & 1) * 32, nsub0 = (wave >> 1) * 32;

    // shorts: W0H@0, W0L@2560, W1H@5120, W1L@7680, XsH@10240, XsL@12800
    __shared__ __align__(16) char smem[30720];
    unsigned short* S = (unsigned short*)smem;

    floatx4 acc[2][2][2] = {};   // [sub][i][j]

    const int wm = t >> 2, wk = (t & 3) * 8;       // W load role
    const int xn = t & 63, xc8 = (t >> 6) * 8;     // x transposed-load role

    for (int kc = 0; kc < 8; ++kc) {
        __syncthreads();
#pragma unroll
        for (int sub = 0; sub < 2; ++sub) {
            // W sub-tile: coalesced load + in-reg split -> LDS [m][40] hi/lo
            const float* wsrc = wq +
                (size_t)(region * 128 + sub * 64 + wm) * 256 + kc * 32 + wk;
            float4 w0 = *(const float4*)wsrc;
            float4 w1 = *(const float4*)(wsrc + 4);
            unsigned ph[4], pl[4];
            split_pack(w0.x, w0.y, ph[0], pl[0]);
            split_pack(w0.z, w0.w, ph[1], pl[1]);
            split_pack(w1.x, w1.y, ph[2], pl[2]);
            split_pack(w1.z, w1.w, ph[3], pl[3]);
            *(uint4*)(S + sub * 5120 +        wm * 40 + wk) = *(uint4*)ph;
            *(uint4*)(S + sub * 5120 + 2560 + wm * 40 + wk) = *(uint4*)pl;
        }
        {   // x chunk: transposed loads (coalesced in n) + split -> [n][40]
            const float* xsrc = x + ((size_t)b * 256 + kc * 32 + xc8) * N
                                  + col0 + xn;
            float v[8];
#pragma unroll
            for (int i = 0; i < 8; ++i) v[i] = xsrc[(size_t)i * N];
            unsigned ph[4], pl[4];
            split_pack(v[0], v[1], ph[0], pl[0]);
            split_pack(v[2], v[3], ph[1], pl[1]);
            split_pack(v[4], v[5], ph[2], pl[2]);
            split_pack(v[6], v[7], ph[3], pl[3]);
            *(uint4*)(S + 10240 + xn * 40 + xc8) = *(uint4*)ph;
            *(uint4*)(S + 12800 + xn * 40 + xc8) = *(uint4*)pl;
        }
        __syncthreads();
        // B fragments: loaded once, reused for both W subs
        short8 bh0 = *(const short8*)(S + 10240 + (nsub0 +      l16) * 40 + quad * 8);
        short8 bh1 = *(const short8*)(S + 10240 + (nsub0 + 16 + l16) * 40 + quad * 8);
        short8 bl0 = *(const short8*)(S + 12800 + (nsub0 +      l16) * 40 + quad * 8);
        short8 bl1 = *(const short8*)(S + 12800 + (nsub0 + 16 + l16) * 40 + quad * 8);
#pragma unroll
        for (int sub = 0; sub < 2; ++sub) {
            const unsigned short* W0 = S + sub * 5120;
            short8 ah0 = *(const short8*)(W0 +        (msub0 +      l16) * 40 + quad * 8);
            short8 ah1 = *(const short8*)(W0 +        (msub0 + 16 + l16) * 40 + quad * 8);
            short8 al0 = *(const short8*)(W0 + 2560 + (msub0 +      l16) * 40 + quad * 8);
            short8 al1 = *(const short8*)(W0 + 2560 + (msub0 + 16 + l16) * 40 + quad * 8);
            acc[sub][0][0] = __builtin_amdgcn_mfma_f32_16x16x32_bf16(ah0, bh0, acc[sub][0][0], 0, 0, 0);
            acc[sub][0][1] = __builtin_amdgcn_mfma_f32_16x16x32_bf16(ah0, bh1, acc[sub][0][1], 0, 0, 0);
            acc[sub][1][0] = __builtin_amdgcn_mfma_f32_16x16x32_bf16(ah1, bh0, acc[sub][1][0], 0, 0, 0);
            acc[sub][1][1] = __builtin_amdgcn_mfma_f32_16x16x32_bf16(ah1, bh1, acc[sub][1][1], 0, 0, 0);
            acc[sub][0][0] = __builtin_amdgcn_mfma_f32_16x16x32_bf16(ah0, bl0, acc[sub][0][0], 0, 0, 0);
            acc[sub][0][1] = __builtin_amdgcn_mfma_f32_16x16x32_bf16(ah0, bl1, acc[sub][0][1], 0, 0, 0);
            acc[sub][1][0] = __builtin_amdgcn_mfma_f32_16x16x32_bf16(ah1, bl0, acc[sub][1][0], 0, 0, 0);
            acc[sub][1][1] = __builtin_amdgcn_mfma_f32_16x16x32_bf16(ah1, bl1, acc[sub][1][1], 0, 0, 0);
            acc[sub][0][0] = __builtin_amdgcn_mfma_f32_16x16x32_bf16(al0, bh0, acc[sub][0][0], 0, 0, 0);
            acc[sub][0][1] = __builtin_amdgcn_mfma_f32_16x16x32_bf16(al0, bh1, acc[sub][0][1], 0, 0, 0);
            acc[sub][1][0] = __builtin_amdgcn_mfma_f32_16x16x32_bf16(al1, bh0, acc[sub][1][0], 0, 0, 0);
            acc[sub][1][1] = __builtin_amdgcn_mfma_f32_16x16x32_bf16(al1, bh1, acc[sub][1][1], 0, 0, 0);
        }
    }

    // ---- epilogue: two passes, each the proven 64-row epilogue ----
#pragma unroll 1
    for (int sub = 0; sub < 2; ++sub) {
        __syncthreads();
        const int row0 = region * 128 + sub * 64;
        if (region == 2) {
            float (*LdsF)[68] = (float(*)[68])smem;
#pragma unroll
            for (int i = 0; i < 2; ++i)
#pragma unroll
                for (int j = 0; j < 2; ++j) {
                    const int m = msub0 + i * 16 + quad * 4;
                    const int n = nsub0 + j * 16 + l16;
#pragma unroll
                    for (int r = 0; r < 4; ++r) LdsF[m + r][n] = acc[sub][i][j][r];
                }
            __syncthreads();
            const int m = t >> 2, nb2 = (t & 3) * 16;
            const int vrow = b * 128 + (row0 - 256) + m;
            unsigned pk[8];
#pragma unroll
            for (int q = 0; q < 8; ++q)
                pk[q] = pack_rnd(LdsF[m][nb2 + 2 * q], LdsF[m][nb2 + 2 * q + 1]);
            unsigned short* dst = Vp + (size_t)vrow * N + col0 + nb2;
            *(uint4*)&dst[0] = *(uint4*)&pk[0];
            *(uint4*)&dst[8] = *(uint4*)&pk[4];
        } else {
            unsigned short (*LdsT)[68] = (unsigned short(*)[68])smem;
            const float sc = region ? 1.0f
                                    : (0.17677669529663687f * 1.4426950408889634f);
#pragma unroll
            for (int i = 0; i < 2; ++i)
#pragma unroll
                for (int j = 0; j < 2; ++j) {
                    const int m = msub0 + i * 16 + quad * 4;
                    const int n = nsub0 + j * 16 + l16;
                    uint2 pr;
                    pr.x = pack_rnd(acc[sub][i][j][0] * sc, acc[sub][i][j][1] * sc);
                    pr.y = pack_rnd(acc[sub][i][j][2] * sc, acc[sub][i][j][3] * sc);
                    *(uint2*)&LdsT[n][m] = pr;
                }
            __syncthreads();
            const int n = t & 63, hb = (t >> 6) & 1, dh = t >> 7;
            const int h = ((row0 & 127) >> 5) + hb;
            const int m0 = hb * 32 + dh * 16;
            unsigned tmp[8];
            *(uint2*)&tmp[0] = *(const uint2*)&LdsT[n][m0];
            *(uint2*)&tmp[2] = *(const uint2*)&LdsT[n][m0 + 4];
            *(uint2*)&tmp[4] = *(const uint2*)&LdsT[n][m0 + 8];
            *(uint2*)&tmp[6] = *(const uint2*)&LdsT[n][m0 + 12];
            unsigned short* dst = (region ? Kp : Qp) +
                ((size_t)(b * 4 + h) * N + col0 + n) * 32 + dh * 16;
            *(uint4*)&dst[0] = *(uint4*)&tmp[0];
            *(uint4*)&dst[8] = *(uint4*)&tmp[4];
        }
    }
}

// ---------------------------------------------------------------------------
// MFMA flash attention -- EXACT round-3 form (proven 55.8 us).  Q-tile 128,
// grid (32 i0, 16 bh), single dispatch (round-8 split cost +8 us tail).
// ---------------------------------------------------------------------------
__global__ __launch_bounds__(512) void attn_fused(
    const unsigned short* __restrict__ Qp,
    const unsigned short* __restrict__ Kp,
    const unsigned short* __restrict__ Vp,
    unsigned short* __restrict__ Oth, unsigned short* __restrict__ Otl)
{
    const int N = N_TOK;
    const int bh = blockIdx.y;
    const int b = bh >> 2, h = bh & 3;
    const int i0 = blockIdx.x * 128;
    const int t = threadIdx.x;
    const int wave = t >> 6, lane = t & 63;
    const int l16 = lane & 15, quad = lane >> 4;
    const int team = wave >> 2, w4 = wave & 3;

    __shared__ __align__(16) char smem[38912];
    unsigned short* S = (unsigned short*)smem;

    short8 ones;
#pragma unroll
    for (int e = 0; e < 8; ++e) ones[e] = (short)0x3F80;

    short8 qh[2];
#pragma unroll
    for (int g = 0; g < 2; ++g)
        qh[g] = *(const short8*)(Qp +
            ((size_t)bh * N + i0 + w4 * 32 + g * 16 + l16) * 32 + quad * 8);

    floatx4 o[2][2] = {};
    floatx4 lacc[2] = {};

    const int st_k = t & 255;
    const int skey = st_k >> 2, sdp = (st_k & 3) * 8;
    const int sslot = (skey & 32) | ((skey & 4) << 2) | ((skey & 24) >> 1)
                    | (skey & 3);
    const int svd = st_k >> 3, svp = (st_k & 7) * 8;
    const unsigned short* kp0 = Kp + ((size_t)bh * N + skey) * 32 + sdp;
    const unsigned short* kp1 = kp0 + (size_t)2048 * 32;
    const unsigned short* vp0 = Vp + ((size_t)bh * 32 + svd) * N + svp;
    const unsigned short* vp1 = vp0 + 2048;

    short8 r0, r1;
    if (t < 256) { r0 = *(const short8*)kp0; r1 = *(const short8*)kp1; }
    else         { r0 = *(const short8*)vp0; r1 = *(const short8*)vp1; }
    if (t < 256) {
        *(short8*)(S + sslot * 40 + sdp) = r0;
        *(short8*)(S + 2560 + sslot * 40 + sdp) = r1;
    } else {
        *(short8*)(S + 10240 + svd * 72 + svp) = r0;
        *(short8*)(S + 10240 + 2304 + svd * 72 + svp) = r1;
    }
    kp0 += 64 * 32; kp1 += 64 * 32; vp0 += 64; vp1 += 64;
    if (t < 256) { r0 = *(const short8*)kp0; r1 = *(const short8*)kp1; }
    else         { r0 = *(const short8*)vp0; r1 = *(const short8*)vp1; }
    __syncthreads();

    for (int it = 0; it < 32; ++it) {
        const int cur = it & 1;
        if (it + 1 < 32) {
            const int nb = 1 - cur;
            if (t < 256) {
                *(short8*)(S + nb * 5120 + sslot * 40 + sdp) = r0;
                *(short8*)(S + nb * 5120 + 2560 + sslot * 40 + sdp) = r1;
            } else {
                *(short8*)(S + 10240 + nb * 4608 + svd * 72 + svp) = r0;
                *(short8*)(S + 10240 + nb * 4608 + 2304 + svd * 72 + svp) = r1;
            }
        }
        if (it + 2 < 32) {
            kp0 += 64 * 32; kp1 += 64 * 32; vp0 += 64; vp1 += 64;
            if (t < 256) { r0 = *(const short8*)kp0; r1 = *(const short8*)kp1; }
            else         { r0 = *(const short8*)vp0; r1 = *(const short8*)vp1; }
        }

        const unsigned short* Ksr = S + cur * 5120 + team * 2560;
        const unsigned short* Vsr = S + 10240 + cur * 4608 + team * 2304;

        short8 kh0 = *(const short8*)(Ksr + ( 0 + l16) * 40 + quad * 8);
        short8 kh1 = *(const short8*)(Ksr + (16 + l16) * 40 + quad * 8);
        short8 kh2 = *(const short8*)(Ksr + (32 + l16) * 40 + quad * 8);
        short8 kh3 = *(const short8*)(Ksr + (48 + l16) * 40 + quad * 8);
        short8 vh00 = *(const short8*)(Vsr + ( 0 + l16) * 72 +  0 + quad * 8);
        short8 vh01 = *(const short8*)(Vsr + (16 + l16) * 72 +  0 + quad * 8);
        short8 vh10 = *(const short8*)(Vsr + ( 0 + l16) * 72 + 32 + quad * 8);
        short8 vh11 = *(const short8*)(Vsr + (16 + l16) * 72 + 32 + quad * 8);

#pragma unroll
        for (int g = 0; g < 2; ++g) {
            const floatx4 z = {0.0f, 0.0f, 0.0f, 0.0f};
            floatx4 s0 = __builtin_amdgcn_mfma_f32_16x16x32_bf16(kh0, qh[g], z, 0, 0, 0);
            floatx4 s1 = __builtin_amdgcn_mfma_f32_16x16x32_bf16(kh1, qh[g], z, 0, 0, 0);
            floatx4 s2 = __builtin_amdgcn_mfma_f32_16x16x32_bf16(kh2, qh[g], z, 0, 0, 0);
            floatx4 s3 = __builtin_amdgcn_mfma_f32_16x16x32_bf16(kh3, qh[g], z, 0, 0, 0);
            short8 pf0 = mk_short8(
                pack_rnd(fast_exp2(s0[0]), fast_exp2(s0[1])),
                pack_rnd(fast_exp2(s0[2]), fast_exp2(s0[3])),
                pack_rnd(fast_exp2(s1[0]), fast_exp2(s1[1])),
                pack_rnd(fast_exp2(s1[2]), fast_exp2(s1[3])));
            o[g][0] = __builtin_amdgcn_mfma_f32_16x16x32_bf16(vh00, pf0, o[g][0], 0, 0, 0);
            o[g][1] = __builtin_amdgcn_mfma_f32_16x16x32_bf16(vh01, pf0, o[g][1], 0, 0, 0);
            lacc[g] = __builtin_amdgcn_mfma_f32_16x16x32_bf16(ones, pf0, lacc[g], 0, 0, 0);
            short8 pf1 = mk_short8(
                pack_rnd(fast_exp2(s2[0]), fast_exp2(s2[1])),
                pack_rnd(fast_exp2(s2[2]), fast_exp2(s2[3])),
                pack_rnd(fast_exp2(s3[0]), fast_exp2(s3[1])),
                pack_rnd(fast_exp2(s3[2]), fast_exp2(s3[3])));
            o[g][0] = __builtin_amdgcn_mfma_f32_16x16x32_bf16(vh10, pf1, o[g][0], 0, 0, 0);
            o[g][1] = __builtin_amdgcn_mfma_f32_16x16x32_bf16(vh11, pf1, o[g][1], 0, 0, 0);
            lacc[g] = __builtin_amdgcn_mfma_f32_16x16x32_bf16(ones, pf1, lacc[g], 0, 0, 0);
        }
        __syncthreads();
    }

    float (*OfB)[132] = (float(*)[132])smem;
    float* Lb = (float*)(smem + 16896);
    float (*OfA)[132] = (float(*)[132])(smem + 17408);

    if (team == 1) {
#pragma unroll
        for (int g = 0; g < 2; ++g) {
            const int q = w4 * 32 + g * 16 + l16;
#pragma unroll
            for (int half = 0; half < 2; ++half)
#pragma unroll
                for (int r = 0; r < 4; ++r)
                    OfB[half * 16 + quad * 4 + r][q] = o[g][half][r];
            if (quad == 0) Lb[q] = lacc[g][0];
        }
    }
    __syncthreads();
    if (team == 0) {
#pragma unroll
        for (int g = 0; g < 2; ++g) {
            const int q = w4 * 32 + g * 16 + l16;
            const float inv = 1.0f / (lacc[g][0] + Lb[q]);
#pragma unroll
            for (int half = 0; half < 2; ++half)
#pragma unroll
                for (int r = 0; r < 4; ++r) {
                    const int d = half * 16 + quad * 4 + r;
                    OfA[d][q] = (o[g][half][r] + OfB[d][q]) * inv;
                }
        }
    }
    __syncthreads();
    {
        const int q = t >> 2, db = (t & 3) * 8;
        unsigned ph[4], pl[4];
#pragma unroll
        for (int i = 0; i < 4; ++i)
            split_pack(OfA[db + 2 * i][q], OfA[db + 2 * i + 1][q], ph[i], pl[i]);
        const size_t off = ((size_t)b * N + i0 + q) * 128 + h * 32 + db;
        *(uint4*)(Oth + off) = *(uint4*)ph;
        *(uint4*)(Otl + off) = *(uint4*)pl;
    }
}

// ---------------------------------------------------------------------------
// Output GEMM -- EXACT round-3/6 form (proven in the 152.5 us run).
// Grid (64 n, 4 m, 4 b), 256 threads.
// ---------------------------------------------------------------------------
__global__ __launch_bounds__(256) void gemm2_fused(
    const float* __restrict__ wo,
    const unsigned short* __restrict__ Oth, const unsigned short* __restrict__ Otl,
    const float* __restrict__ bias, float* __restrict__ y)
{
    const int N = N_TOK;
    const int b = blockIdx.z;
    const int row0 = blockIdx.y * 64;
    const int col0 = blockIdx.x * 64;
    const int t = threadIdx.x;
    const int wave = t >> 6, lane = t & 63;
    const int l16 = lane & 15, quad = lane >> 4;
    const int msub0 = (wave & 1) * 32, nsub0 = (wave >> 1) * 32;

    __shared__ __align__(16) char smem[17408];
    unsigned short* BsH = (unsigned short*)smem;           // [64][40]
    unsigned short* BsL = (unsigned short*)(smem + 5120);  // [64][40]
    float (*LdsF)[68] = (float(*)[68])smem;                // epilogue reuse

    short8 ah[4][2], al[4][2];
#pragma unroll
    for (int kc = 0; kc < 4; ++kc)
#pragma unroll
        for (int r = 0; r < 2; ++r)
            cvt_frag(wo + (size_t)(row0 + msub0 + r * 16 + l16) * 128 +
                         kc * 32 + quad * 8,
                     ah[kc][r], al[kc][r]);

    const int srow = t >> 2, sk = (t & 3) * 8;
    const unsigned short* gH = Oth + ((size_t)b * N + col0 + srow) * 128 + sk;
    const unsigned short* gL = Otl + ((size_t)b * N + col0 + srow) * 128 + sk;

    floatx4 acc[2][2] = {};
#pragma unroll
    for (int kc = 0; kc < 4; ++kc) {
        short8 hreg = *(const short8*)(gH + kc * 32);
        short8 lreg = *(const short8*)(gL + kc * 32);
        __syncthreads();
        *(short8*)(BsH + srow * 40 + sk) = hreg;
        *(short8*)(BsL + srow * 40 + sk) = lreg;
        __syncthreads();
        short8 bh0 = *(const short8*)(BsH + (nsub0 + l16) * 40 + quad * 8);
        short8 bh1 = *(const short8*)(BsH + (nsub0 + 16 + l16) * 40 + quad * 8);
        short8 bl0 = *(const short8*)(BsL + (nsub0 + l16) * 40 + quad * 8);
        short8 bl1 = *(const short8*)(BsL + (nsub0 + 16 + l16) * 40 + quad * 8);
        acc[0][0] = __builtin_amdgcn_mfma_f32_16x16x32_bf16(ah[kc][0], bh0, acc[0][0], 0, 0, 0);
        acc[0][1] = __builtin_amdgcn_mfma_f32_16x16x32_bf16(ah[kc][0], bh1, acc[0][1], 0, 0, 0);
        acc[1][0] = __builtin_amdgcn_mfma_f32_16x16x32_bf16(ah[kc][1], bh0, acc[1][0], 0, 0, 0);
        acc[1][1] = __builtin_amdgcn_mfma_f32_16x16x32_bf16(ah[kc][1], bh1, acc[1][1], 0, 0, 0);
        acc[0][0] = __builtin_amdgcn_mfma_f32_16x16x32_bf16(ah[kc][0], bl0, acc[0][0], 0, 0, 0);
        acc[0][1] = __builtin_amdgcn_mfma_f32_16x16x32_bf16(ah[kc][0], bl1, acc[0][1], 0, 0, 0);
        acc[1][0] = __builtin_amdgcn_mfma_f32_16x16x32_bf16(ah[kc][1], bl0, acc[1][0], 0, 0, 0);
        acc[1][1] = __builtin_amdgcn_mfma_f32_16x16x32_bf16(ah[kc][1], bl1, acc[1][1], 0, 0, 0);
        acc[0][0] = __builtin_amdgcn_mfma_f32_16x16x32_bf16(al[kc][0], bh0, acc[0][0], 0, 0, 0);
        acc[0][1] = __builtin_amdgcn_mfma_f32_16x16x32_bf16(al[kc][0], bh1, acc[0][1], 0, 0, 0);
        acc[1][0] = __builtin_amdgcn_mfma_f32_16x16x32_bf16(al[kc][1], bh0, acc[1][0], 0, 0, 0);
        acc[1][1] = __builtin_amdgcn_mfma_f32_16x16x32_bf16(al[kc][1], bh1, acc[1][1], 0, 0, 0);
    }

    __syncthreads();
#pragma unroll
    for (int i = 0; i < 2; ++i)
#pragma unroll
        for (int j = 0; j < 2; ++j) {
            const int m = msub0 + i * 16 + quad * 4;
            const int n = nsub0 + j * 16 + l16;
#pragma unroll
            for (int r = 0; r < 4; ++r) LdsF[m + r][n] = acc[i][j][r];
        }
    __syncthreads();
    const int m = t >> 2, nb = (t & 3) * 16;
    const float bv = bias[row0 + m];
    float* dst = y + ((size_t)b * 256 + row0 + m) * N + col0 + nb;
#pragma unroll
    for (int g = 0; g < 4; ++g) {
        float4 o4;
        o4.x = LdsF[m][nb + g * 4 + 0] + bv;
        o4.y = LdsF[m][nb + g * 4 + 1] + bv;
        o4.z = LdsF[m][nb + g * 4 + 2] + bv;
        o4.w = LdsF[m][nb + g * 4 + 3] + bv;
        *(float4*)(dst + g * 4) = o4;
    }
}

extern "C" void kernel_launch(void* const* d_in, const int* in_sizes, int n_in,
                              void* d_out, int out_size, void* d_ws, size_t ws_size,
                              hipStream_t stream) {
    const float* x     = (const float*)d_in[0];
    const float* w_qkv = (const float*)d_in[1];
    const float* w_out = (const float*)d_in[2];
    const float* b_out = (const float*)d_in[3];
    float* y = (float*)d_out;

    // workspace 20 MiB: Qp, Kp, Vp, Oth, Otl (4 MiB each)
    char* base = (char*)d_ws;
    unsigned short* Qp  = (unsigned short*)base;
    unsigned short* Kp  = Qp + (size_t)16 * N_TOK * 32;
    unsigned short* Vp  = Kp + (size_t)16 * N_TOK * 32;
    unsigned short* Oth = Vp + (size_t)16 * N_TOK * 32;
    unsigned short* Otl = Oth + (size_t)BATCH * N_TOK * 128;

    gemm1_fused<<<dim3(64, 3, BATCH), dim3(256), 0, stream>>>(
        w_qkv, x, Qp, Kp, Vp);
    attn_fused<<<dim3(32, 16), dim3(512), 0, stream>>>(Qp, Kp, Vp, Oth, Otl);
    gemm2_fused<<<dim3(64, 4, BATCH), dim3(256), 0, stream>>>(
        w_out, Oth, Otl, b_out, y);
}

// Round 10
// 150.761 us; speedup vs baseline: 1.3483x; 1.3483x over previous
//
#include <hip/hip_runtime.h>

#define N_TOK 4096
#define BATCH 4

typedef __attribute__((ext_vector_type(8))) short short8;
typedef __attribute__((ext_vector_type(4))) float floatx4;

// Pack two floats to packed bf16 pair (round-half-away): 3 VALU ops.
__device__ __forceinline__ unsigned pack_rnd(float a, float b) {
    unsigned ra = __float_as_uint(a) + 0x8000u;
    unsigned rb = __float_as_uint(b) + 0x8000u;
    return __builtin_amdgcn_perm(rb, ra, 0x07060302u);
}

// Split two floats into bf16 hi-pair and lo-pair.
__device__ __forceinline__ void split_pack(float a, float b,
                                           unsigned &ph, unsigned &pl) {
    unsigned ra = __float_as_uint(a) + 0x8000u;
    unsigned rb = __float_as_uint(b) + 0x8000u;
    ph = __builtin_amdgcn_perm(rb, ra, 0x07060302u);
    float la = a - __uint_as_float(ra & 0xffff0000u);
    float lb = b - __uint_as_float(rb & 0xffff0000u);
    pl = __builtin_amdgcn_perm(__float_as_uint(lb) + 0x8000u,
                               __float_as_uint(la) + 0x8000u, 0x07060302u);
}

__device__ __forceinline__ short8 mk_short8(unsigned p0, unsigned p1,
                                            unsigned p2, unsigned p3) {
    union { unsigned u[4]; short8 s; } c;
    c.u[0] = p0; c.u[1] = p1; c.u[2] = p2; c.u[3] = p3;
    return c.s;
}

// Convert 8 consecutive fp32 (two float4) into hi/lo short8 fragments.
__device__ __forceinline__ void cvt_frag(const float* src,
                                         short8 &hi, short8 &lo) {
    float4 w0 = *(const float4*)src;
    float4 w1 = *(const float4*)(src + 4);
    unsigned ph[4], pl[4];
    split_pack(w0.x, w0.y, ph[0], pl[0]);
    split_pack(w0.z, w0.w, ph[1], pl[1]);
    split_pack(w1.x, w1.y, ph[2], pl[2]);
    split_pack(w1.z, w1.w, ph[3], pl[3]);
    hi = mk_short8(ph[0], ph[1], ph[2], ph[3]);
    lo = mk_short8(pl[0], pl[1], pl[2], pl[3]);
}

__device__ __forceinline__ float fast_exp2(float x) {
#if __has_builtin(__builtin_amdgcn_exp2f)
    return __builtin_amdgcn_exp2f(x);
#else
    return exp2f(x);
#endif
}

// ---------------------------------------------------------------------------
// QKV GEMM, region-merged (x staged ONCE per 128-row region, B fragments
// reused for both 64-row W subs).  Round-9's 82us/178MB-write regression was
// a SCRATCH SPILL from the runtime-indexed acc[sub][i][j] in the
// `#pragma unroll 1` epilogue loop (rule: runtime-indexed vector arrays go
// to scratch).  This round: two NAMED accumulator arrays (acc0/acc1) with
// fully-inlined lambdas -> every index compile-time static -> registers.
// Numerics/order identical -> absmax must be 3.051758e-05.
// LDS 30720 B.  Grid (64 n, 3 region, 4 b), 256 threads.
// ---------------------------------------------------------------------------
__global__ __launch_bounds__(256) void gemm1_fused(
    const float* __restrict__ wq, const float* __restrict__ x,
    unsigned short* __restrict__ Qp, unsigned short* __restrict__ Kp,
    unsigned short* __restrict__ Vp)
{
    const int N = N_TOK;
    const int b = blockIdx.z;
    const int region = blockIdx.y;            // 0=Q, 1=K, 2=V
    const int col0 = blockIdx.x * 64;
    const int t = threadIdx.x;
    const int wave = t >> 6, lane = t & 63;
    const int l16 = lane & 15, quad = lane >> 4;
    const int msub0 = (wave & 1) * 32, nsub0 = (wave >> 1) * 32;

    // shorts: W0H@0, W0L@2560, W1H@5120, W1L@7680, XsH@10240, XsL@12800
    __shared__ __align__(16) char smem[30720];
    unsigned short* S = (unsigned short*)smem;

    floatx4 acc0[2][2] = {};   // sub 0 (rows region*128 ..  +63)
    floatx4 acc1[2][2] = {};   // sub 1 (rows region*128+64.. +127)

    const int wm = t >> 2, wk = (t & 3) * 8;       // W load role
    const int xn = t & 63, xc8 = (t >> 6) * 8;     // x transposed-load role

    for (int kc = 0; kc < 8; ++kc) {
        __syncthreads();
        {   // W sub-tile 0
            const float* wsrc = wq +
                (size_t)(region * 128 + wm) * 256 + kc * 32 + wk;
            float4 w0 = *(const float4*)wsrc;
            float4 w1 = *(const float4*)(wsrc + 4);
            unsigned ph[4], pl[4];
            split_pack(w0.x, w0.y, ph[0], pl[0]);
            split_pack(w0.z, w0.w, ph[1], pl[1]);
            split_pack(w1.x, w1.y, ph[2], pl[2]);
            split_pack(w1.z, w1.w, ph[3], pl[3]);
            *(uint4*)(S +        wm * 40 + wk) = *(uint4*)ph;
            *(uint4*)(S + 2560 + wm * 40 + wk) = *(uint4*)pl;
        }
        {   // W sub-tile 1
            const float* wsrc = wq +
                (size_t)(region * 128 + 64 + wm) * 256 + kc * 32 + wk;
            float4 w0 = *(const float4*)wsrc;
            float4 w1 = *(const float4*)(wsrc + 4);
            unsigned ph[4], pl[4];
            split_pack(w0.x, w0.y, ph[0], pl[0]);
            split_pack(w0.z, w0.w, ph[1], pl[1]);
            split_pack(w1.x, w1.y, ph[2], pl[2]);
            split_pack(w1.z, w1.w, ph[3], pl[3]);
            *(uint4*)(S + 5120 + wm * 40 + wk) = *(uint4*)ph;
            *(uint4*)(S + 7680 + wm * 40 + wk) = *(uint4*)pl;
        }
        {   // x chunk: transposed loads (coalesced in n) + split -> [n][40]
            const float* xsrc = x + ((size_t)b * 256 + kc * 32 + xc8) * N
                                  + col0 + xn;
            float v[8];
#pragma unroll
            for (int i = 0; i < 8; ++i) v[i] = xsrc[(size_t)i * N];
            unsigned ph[4], pl[4];
            split_pack(v[0], v[1], ph[0], pl[0]);
            split_pack(v[2], v[3], ph[1], pl[1]);
            split_pack(v[4], v[5], ph[2], pl[2]);
            split_pack(v[6], v[7], ph[3], pl[3]);
            *(uint4*)(S + 10240 + xn * 40 + xc8) = *(uint4*)ph;
            *(uint4*)(S + 12800 + xn * 40 + xc8) = *(uint4*)pl;
        }
        __syncthreads();
        // B fragments: loaded once, reused for both W subs
        short8 bh0 = *(const short8*)(S + 10240 + (nsub0 +      l16) * 40 + quad * 8);
        short8 bh1 = *(const short8*)(S + 10240 + (nsub0 + 16 + l16) * 40 + quad * 8);
        short8 bl0 = *(const short8*)(S + 12800 + (nsub0 +      l16) * 40 + quad * 8);
        short8 bl1 = *(const short8*)(S + 12800 + (nsub0 + 16 + l16) * 40 + quad * 8);

        auto mfma_sub = [&](floatx4 (&A)[2][2], const unsigned short* W0) {
            short8 ah0 = *(const short8*)(W0 +        (msub0 +      l16) * 40 + quad * 8);
            short8 ah1 = *(const short8*)(W0 +        (msub0 + 16 + l16) * 40 + quad * 8);
            short8 al0 = *(const short8*)(W0 + 2560 + (msub0 +      l16) * 40 + quad * 8);
            short8 al1 = *(const short8*)(W0 + 2560 + (msub0 + 16 + l16) * 40 + quad * 8);
            A[0][0] = __builtin_amdgcn_mfma_f32_16x16x32_bf16(ah0, bh0, A[0][0], 0, 0, 0);
            A[0][1] = __builtin_amdgcn_mfma_f32_16x16x32_bf16(ah0, bh1, A[0][1], 0, 0, 0);
            A[1][0] = __builtin_amdgcn_mfma_f32_16x16x32_bf16(ah1, bh0, A[1][0], 0, 0, 0);
            A[1][1] = __builtin_amdgcn_mfma_f32_16x16x32_bf16(ah1, bh1, A[1][1], 0, 0, 0);
            A[0][0] = __builtin_amdgcn_mfma_f32_16x16x32_bf16(ah0, bl0, A[0][0], 0, 0, 0);
            A[0][1] = __builtin_amdgcn_mfma_f32_16x16x32_bf16(ah0, bl1, A[0][1], 0, 0, 0);
            A[1][0] = __builtin_amdgcn_mfma_f32_16x16x32_bf16(ah1, bl0, A[1][0], 0, 0, 0);
            A[1][1] = __builtin_amdgcn_mfma_f32_16x16x32_bf16(ah1, bl1, A[1][1], 0, 0, 0);
            A[0][0] = __builtin_amdgcn_mfma_f32_16x16x32_bf16(al0, bh0, A[0][0], 0, 0, 0);
            A[0][1] = __builtin_amdgcn_mfma_f32_16x16x32_bf16(al0, bh1, A[0][1], 0, 0, 0);
            A[1][0] = __builtin_amdgcn_mfma_f32_16x16x32_bf16(al1, bh0, A[1][0], 0, 0, 0);
            A[1][1] = __builtin_amdgcn_mfma_f32_16x16x32_bf16(al1, bh1, A[1][1], 0, 0, 0);
        };
        mfma_sub(acc0, S);
        mfma_sub(acc1, S + 5120);
    }

    // ---- epilogue: two static passes of the proven 64-row epilogue ----
    auto epi = [&](floatx4 (&A)[2][2], const int row0) {
        __syncthreads();
        if (region == 2) {
            float (*LdsF)[68] = (float(*)[68])smem;
#pragma unroll
            for (int i = 0; i < 2; ++i)
#pragma unroll
                for (int j = 0; j < 2; ++j) {
                    const int m = msub0 + i * 16 + quad * 4;
                    const int n = nsub0 + j * 16 + l16;
#pragma unroll
                    for (int r = 0; r < 4; ++r) LdsF[m + r][n] = A[i][j][r];
                }
            __syncthreads();
            const int m = t >> 2, nb2 = (t & 3) * 16;
            const int vrow = b * 128 + (row0 - 256) + m;
            unsigned pk[8];
#pragma unroll
            for (int q = 0; q < 8; ++q)
                pk[q] = pack_rnd(LdsF[m][nb2 + 2 * q], LdsF[m][nb2 + 2 * q + 1]);
            unsigned short* dst = Vp + (size_t)vrow * N + col0 + nb2;
            *(uint4*)&dst[0] = *(uint4*)&pk[0];
            *(uint4*)&dst[8] = *(uint4*)&pk[4];
        } else {
            unsigned short (*LdsT)[68] = (unsigned short(*)[68])smem;
            const float sc = region ? 1.0f
                                    : (0.17677669529663687f * 1.4426950408889634f);
#pragma unroll
            for (int i = 0; i < 2; ++i)
#pragma unroll
                for (int j = 0; j < 2; ++j) {
                    const int m = msub0 + i * 16 + quad * 4;
                    const int n = nsub0 + j * 16 + l16;
                    uint2 pr;
                    pr.x = pack_rnd(A[i][j][0] * sc, A[i][j][1] * sc);
                    pr.y = pack_rnd(A[i][j][2] * sc, A[i][j][3] * sc);
                    *(uint2*)&LdsT[n][m] = pr;
                }
            __syncthreads();
            const int n = t & 63, hb = (t >> 6) & 1, dh = t >> 7;
            const int h = ((row0 & 127) >> 5) + hb;
            const int m0 = hb * 32 + dh * 16;
            unsigned tmp[8];
            *(uint2*)&tmp[0] = *(const uint2*)&LdsT[n][m0];
            *(uint2*)&tmp[2] = *(const uint2*)&LdsT[n][m0 + 4];
            *(uint2*)&tmp[4] = *(const uint2*)&LdsT[n][m0 + 8];
            *(uint2*)&tmp[6] = *(const uint2*)&LdsT[n][m0 + 12];
            unsigned short* dst = (region ? Kp : Qp) +
                ((size_t)(b * 4 + h) * N + col0 + n) * 32 + dh * 16;
            *(uint4*)&dst[0] = *(uint4*)&tmp[0];
            *(uint4*)&dst[8] = *(uint4*)&tmp[4];
        }
    };
    epi(acc0, region * 128);
    epi(acc1, region * 128 + 64);
}

// ---------------------------------------------------------------------------
// MFMA flash attention -- EXACT round-3 form (proven 55.8 us).  Q-tile 128,
// grid (32 i0, 16 bh), single dispatch.
// ---------------------------------------------------------------------------
__global__ __launch_bounds__(512) void attn_fused(
    const unsigned short* __restrict__ Qp,
    const unsigned short* __restrict__ Kp,
    const unsigned short* __restrict__ Vp,
    unsigned short* __restrict__ Oth, unsigned short* __restrict__ Otl)
{
    const int N = N_TOK;
    const int bh = blockIdx.y;
    const int b = bh >> 2, h = bh & 3;
    const int i0 = blockIdx.x * 128;
    const int t = threadIdx.x;
    const int wave = t >> 6, lane = t & 63;
    const int l16 = lane & 15, quad = lane >> 4;
    const int team = wave >> 2, w4 = wave & 3;

    __shared__ __align__(16) char smem[38912];
    unsigned short* S = (unsigned short*)smem;

    short8 ones;
#pragma unroll
    for (int e = 0; e < 8; ++e) ones[e] = (short)0x3F80;

    short8 qh[2];
#pragma unroll
    for (int g = 0; g < 2; ++g)
        qh[g] = *(const short8*)(Qp +
            ((size_t)bh * N + i0 + w4 * 32 + g * 16 + l16) * 32 + quad * 8);

    floatx4 o[2][2] = {};
    floatx4 lacc[2] = {};

    const int st_k = t & 255;
    const int skey = st_k >> 2, sdp = (st_k & 3) * 8;
    const int sslot = (skey & 32) | ((skey & 4) << 2) | ((skey & 24) >> 1)
                    | (skey & 3);
    const int svd = st_k >> 3, svp = (st_k & 7) * 8;
    const unsigned short* kp0 = Kp + ((size_t)bh * N + skey) * 32 + sdp;
    const unsigned short* kp1 = kp0 + (size_t)2048 * 32;
    const unsigned short* vp0 = Vp + ((size_t)bh * 32 + svd) * N + svp;
    const unsigned short* vp1 = vp0 + 2048;

    short8 r0, r1;
    if (t < 256) { r0 = *(const short8*)kp0; r1 = *(const short8*)kp1; }
    else         { r0 = *(const short8*)vp0; r1 = *(const short8*)vp1; }
    if (t < 256) {
        *(short8*)(S + sslot * 40 + sdp) = r0;
        *(short8*)(S + 2560 + sslot * 40 + sdp) = r1;
    } else {
        *(short8*)(S + 10240 + svd * 72 + svp) = r0;
        *(short8*)(S + 10240 + 2304 + svd * 72 + svp) = r1;
    }
    kp0 += 64 * 32; kp1 += 64 * 32; vp0 += 64; vp1 += 64;
    if (t < 256) { r0 = *(const short8*)kp0; r1 = *(const short8*)kp1; }
    else         { r0 = *(const short8*)vp0; r1 = *(const short8*)vp1; }
    __syncthreads();

    for (int it = 0; it < 32; ++it) {
        const int cur = it & 1;
        if (it + 1 < 32) {
            const int nb = 1 - cur;
            if (t < 256) {
                *(short8*)(S + nb * 5120 + sslot * 40 + sdp) = r0;
                *(short8*)(S + nb * 5120 + 2560 + sslot * 40 + sdp) = r1;
            } else {
                *(short8*)(S + 10240 + nb * 4608 + svd * 72 + svp) = r0;
                *(short8*)(S + 10240 + nb * 4608 + 2304 + svd * 72 + svp) = r1;
            }
        }
        if (it + 2 < 32) {
            kp0 += 64 * 32; kp1 += 64 * 32; vp0 += 64; vp1 += 64;
            if (t < 256) { r0 = *(const short8*)kp0; r1 = *(const short8*)kp1; }
            else         { r0 = *(const short8*)vp0; r1 = *(const short8*)vp1; }
        }

        const unsigned short* Ksr = S + cur * 5120 + team * 2560;
        const unsigned short* Vsr = S + 10240 + cur * 4608 + team * 2304;

        short8 kh0 = *(const short8*)(Ksr + ( 0 + l16) * 40 + quad * 8);
        short8 kh1 = *(const short8*)(Ksr + (16 + l16) * 40 + quad * 8);
        short8 kh2 = *(const short8*)(Ksr + (32 + l16) * 40 + quad * 8);
        short8 kh3 = *(const short8*)(Ksr + (48 + l16) * 40 + quad * 8);
        short8 vh00 = *(const short8*)(Vsr + ( 0 + l16) * 72 +  0 + quad * 8);
        short8 vh01 = *(const short8*)(Vsr + (16 + l16) * 72 +  0 + quad * 8);
        short8 vh10 = *(const short8*)(Vsr + ( 0 + l16) * 72 + 32 + quad * 8);
        short8 vh11 = *(const short8*)(Vsr + (16 + l16) * 72 + 32 + quad * 8);

#pragma unroll
        for (int g = 0; g < 2; ++g) {
            const floatx4 z = {0.0f, 0.0f, 0.0f, 0.0f};
            floatx4 s0 = __builtin_amdgcn_mfma_f32_16x16x32_bf16(kh0, qh[g], z, 0, 0, 0);
            floatx4 s1 = __builtin_amdgcn_mfma_f32_16x16x32_bf16(kh1, qh[g], z, 0, 0, 0);
            floatx4 s2 = __builtin_amdgcn_mfma_f32_16x16x32_bf16(kh2, qh[g], z, 0, 0, 0);
            floatx4 s3 = __builtin_amdgcn_mfma_f32_16x16x32_bf16(kh3, qh[g], z, 0, 0, 0);
            short8 pf0 = mk_short8(
                pack_rnd(fast_exp2(s0[0]), fast_exp2(s0[1])),
                pack_rnd(fast_exp2(s0[2]), fast_exp2(s0[3])),
                pack_rnd(fast_exp2(s1[0]), fast_exp2(s1[1])),
                pack_rnd(fast_exp2(s1[2]), fast_exp2(s1[3])));
            o[g][0] = __builtin_amdgcn_mfma_f32_16x16x32_bf16(vh00, pf0, o[g][0], 0, 0, 0);
            o[g][1] = __builtin_amdgcn_mfma_f32_16x16x32_bf16(vh01, pf0, o[g][1], 0, 0, 0);
            lacc[g] = __builtin_amdgcn_mfma_f32_16x16x32_bf16(ones, pf0, lacc[g], 0, 0, 0);
            short8 pf1 = mk_short8(
                pack_rnd(fast_exp2(s2[0]), fast_exp2(s2[1])),
                pack_rnd(fast_exp2(s2[2]), fast_exp2(s2[3])),
                pack_rnd(fast_exp2(s3[0]), fast_exp2(s3[1])),
                pack_rnd(fast_exp2(s3[2]), fast_exp2(s3[3])));
            o[g][0] = __builtin_amdgcn_mfma_f32_16x16x32_bf16(vh10, pf1, o[g][0], 0, 0, 0);
            o[g][1] = __builtin_amdgcn_mfma_f32_16x16x32_bf16(vh11, pf1, o[g][1], 0, 0, 0);
            lacc[g] = __builtin_amdgcn_mfma_f32_16x16x32_bf16(ones, pf1, lacc[g], 0, 0, 0);
        }
        __syncthreads();
    }

    float (*OfB)[132] = (float(*)[132])smem;
    float* Lb = (float*)(smem + 16896);
    float (*OfA)[132] = (float(*)[132])(smem + 17408);

    if (team == 1) {
#pragma unroll
        for (int g = 0; g < 2; ++g) {
            const int q = w4 * 32 + g * 16 + l16;
#pragma unroll
            for (int half = 0; half < 2; ++half)
#pragma unroll
                for (int r = 0; r < 4; ++r)
                    OfB[half * 16 + quad * 4 + r][q] = o[g][half][r];
            if (quad == 0) Lb[q] = lacc[g][0];
        }
    }
    __syncthreads();
    if (team == 0) {
#pragma unroll
        for (int g = 0; g < 2; ++g) {
            const int q = w4 * 32 + g * 16 + l16;
            const float inv = 1.0f / (lacc[g][0] + Lb[q]);
#pragma unroll
            for (int half = 0; half < 2; ++half)
#pragma unroll
                for (int r = 0; r < 4; ++r) {
                    const int d = half * 16 + quad * 4 + r;
                    OfA[d][q] = (o[g][half][r] + OfB[d][q]) * inv;
                }
        }
    }
    __syncthreads();
    {
        const int q = t >> 2, db = (t & 3) * 8;
        unsigned ph[4], pl[4];
#pragma unroll
        for (int i = 0; i < 4; ++i)
            split_pack(OfA[db + 2 * i][q], OfA[db + 2 * i + 1][q], ph[i], pl[i]);
        const size_t off = ((size_t)b * N + i0 + q) * 128 + h * 32 + db;
        *(uint4*)(Oth + off) = *(uint4*)ph;
        *(uint4*)(Otl + off) = *(uint4*)pl;
    }
}

// ---------------------------------------------------------------------------
// Output GEMM -- EXACT round-3/6 form (proven in the 152.5 us run).
// Grid (64 n, 4 m, 4 b), 256 threads.
// ---------------------------------------------------------------------------
__global__ __launch_bounds__(256) void gemm2_fused(
    const float* __restrict__ wo,
    const unsigned short* __restrict__ Oth, const unsigned short* __restrict__ Otl,
    const float* __restrict__ bias, float* __restrict__ y)
{
    const int N = N_TOK;
    const int b = blockIdx.z;
    const int row0 = blockIdx.y * 64;
    const int col0 = blockIdx.x * 64;
    const int t = threadIdx.x;
    const int wave = t >> 6, lane = t & 63;
    const int l16 = lane & 15, quad = lane >> 4;
    const int msub0 = (wave & 1) * 32, nsub0 = (wave >> 1) * 32;

    __shared__ __align__(16) char smem[17408];
    unsigned short* BsH = (unsigned short*)smem;           // [64][40]
    unsigned short* BsL = (unsigned short*)(smem + 5120);  // [64][40]
    float (*LdsF)[68] = (float(*)[68])smem;                // epilogue reuse

    short8 ah[4][2], al[4][2];
#pragma unroll
    for (int kc = 0; kc < 4; ++kc)
#pragma unroll
        for (int r = 0; r < 2; ++r)
            cvt_frag(wo + (size_t)(row0 + msub0 + r * 16 + l16) * 128 +
                         kc * 32 + quad * 8,
                     ah[kc][r], al[kc][r]);

    const int srow = t >> 2, sk = (t & 3) * 8;
    const unsigned short* gH = Oth + ((size_t)b * N + col0 + srow) * 128 + sk;
    const unsigned short* gL = Otl + ((size_t)b * N + col0 + srow) * 128 + sk;

    floatx4 acc[2][2] = {};
#pragma unroll
    for (int kc = 0; kc < 4; ++kc) {
        short8 hreg = *(const short8*)(gH + kc * 32);
        short8 lreg = *(const short8*)(gL + kc * 32);
        __syncthreads();
        *(short8*)(BsH + srow * 40 + sk) = hreg;
        *(short8*)(BsL + srow * 40 + sk) = lreg;
        __syncthreads();
        short8 bh0 = *(const short8*)(BsH + (nsub0 + l16) * 40 + quad * 8);
        short8 bh1 = *(const short8*)(BsH + (nsub0 + 16 + l16) * 40 + quad * 8);
        short8 bl0 = *(const short8*)(BsL + (nsub0 + l16) * 40 + quad * 8);
        short8 bl1 = *(const short8*)(BsL + (nsub0 + 16 + l16) * 40 + quad * 8);
        acc[0][0] = __builtin_amdgcn_mfma_f32_16x16x32_bf16(ah[kc][0], bh0, acc[0][0], 0, 0, 0);
        acc[0][1] = __builtin_amdgcn_mfma_f32_16x16x32_bf16(ah[kc][0], bh1, acc[0][1], 0, 0, 0);
        acc[1][0] = __builtin_amdgcn_mfma_f32_16x16x32_bf16(ah[kc][1], bh0, acc[1][0], 0, 0, 0);
        acc[1][1] = __builtin_amdgcn_mfma_f32_16x16x32_bf16(ah[kc][1], bh1, acc[1][1], 0, 0, 0);
        acc[0][0] = __builtin_amdgcn_mfma_f32_16x16x32_bf16(ah[kc][0], bl0, acc[0][0], 0, 0, 0);
        acc[0][1] = __builtin_amdgcn_mfma_f32_16x16x32_bf16(ah[kc][0], bl1, acc[0][1], 0, 0, 0);
        acc[1][0] = __builtin_amdgcn_mfma_f32_16x16x32_bf16(ah[kc][1], bl0, acc[1][0], 0, 0, 0);
        acc[1][1] = __builtin_amdgcn_mfma_f32_16x16x32_bf16(ah[kc][1], bl1, acc[1][1], 0, 0, 0);
        acc[0][0] = __builtin_amdgcn_mfma_f32_16x16x32_bf16(al[kc][0], bh0, acc[0][0], 0, 0, 0);
        acc[0][1] = __builtin_amdgcn_mfma_f32_16x16x32_bf16(al[kc][0], bh1, acc[0][1], 0, 0, 0);
        acc[1][0] = __builtin_amdgcn_mfma_f32_16x16x32_bf16(al[kc][1], bh0, acc[1][0], 0, 0, 0);
        acc[1][1] = __builtin_amdgcn_mfma_f32_16x16x32_bf16(al[kc][1], bh1, acc[1][1], 0, 0, 0);
    }

    __syncthreads();
#pragma unroll
    for (int i = 0; i < 2; ++i)
#pragma unroll
        for (int j = 0; j < 2; ++j) {
            const int m = msub0 + i * 16 + quad * 4;
            const int n = nsub0 + j * 16 + l16;
#pragma unroll
            for (int r = 0; r < 4; ++r) LdsF[m + r][n] = acc[i][j][r];
        }
    __syncthreads();
    const int m = t >> 2, nb = (t & 3) * 16;
    const float bv = bias[row0 + m];
    float* dst = y + ((size_t)b * 256 + row0 + m) * N + col0 + nb;
#pragma unroll
    for (int g = 0; g < 4; ++g) {
        float4 o4;
        o4.x = LdsF[m][nb + g * 4 + 0] + bv;
        o4.y = LdsF[m][nb + g * 4 + 1] + bv;
        o4.z = LdsF[m][nb + g * 4 + 2] + bv;
        o4.w = LdsF[m][nb + g * 4 + 3] + bv;
        *(float4*)(dst + g * 4) = o4;
    }
}

extern "C" void kernel_launch(void* const* d_in, const int* in_sizes, int n_in,
                              void* d_out, int out_size, void* d_ws, size_t ws_size,
                              hipStream_t stream) {
    const float* x     = (const float*)d_in[0];
    const float* w_qkv = (const float*)d_in[1];
    const float* w_out = (const float*)d_in[2];
    const float* b_out = (const float*)d_in[3];
    float* y = (float*)d_out;

    // workspace 20 MiB: Qp, Kp, Vp, Oth, Otl (4 MiB each)
    char* base = (char*)d_ws;
    unsigned short* Qp  = (unsigned short*)base;
    unsigned short* Kp  = Qp + (size_t)16 * N_TOK * 32;
    unsigned short* Vp  = Kp + (size_t)16 * N_TOK * 32;
    unsigned short* Oth = Vp + (size_t)16 * N_TOK * 32;
    unsigned short* Otl = Oth + (size_t)BATCH * N_TOK * 128;

    gemm1_fused<<<dim3(64, 3, BATCH), dim3(256), 0, stream>>>(
        w_qkv, x, Qp, Kp, Vp);
    attn_fused<<<dim3(32, 16), dim3(512), 0, stream>>>(Qp, Kp, Vp, Oth, Otl);
    gemm2_fused<<<dim3(64, 4, BATCH), dim3(256), 0, stream>>>(
        w_out, Oth, Otl, b_out, y);
}

// Round 11
// 149.015 us; speedup vs baseline: 1.3641x; 1.0117x over previous
//
#include <hip/hip_runtime.h>

#define N_TOK 4096
#define BATCH 4

typedef __attribute__((ext_vector_type(8))) short short8;
typedef __attribute__((ext_vector_type(4))) float floatx4;

// Pack two floats to packed bf16 pair (round-half-away): 3 VALU ops.
__device__ __forceinline__ unsigned pack_rnd(float a, float b) {
    unsigned ra = __float_as_uint(a) + 0x8000u;
    unsigned rb = __float_as_uint(b) + 0x8000u;
    return __builtin_amdgcn_perm(rb, ra, 0x07060302u);
}

// Pack two floats to packed bf16 (RNE) in ONE VALU instruction.
// Convention matches pack_rnd: D.lo = bf16(a), D.hi = bf16(b).
__device__ __forceinline__ unsigned cvt_pk_bf16(float a, float b) {
    unsigned d;
    asm("v_cvt_pk_bf16_f32 %0, %1, %2" : "=v"(d) : "v"(a), "v"(b));
    return d;
}

// Split two floats into bf16 hi-pair and lo-pair.
__device__ __forceinline__ void split_pack(float a, float b,
                                           unsigned &ph, unsigned &pl) {
    unsigned ra = __float_as_uint(a) + 0x8000u;
    unsigned rb = __float_as_uint(b) + 0x8000u;
    ph = __builtin_amdgcn_perm(rb, ra, 0x07060302u);
    float la = a - __uint_as_float(ra & 0xffff0000u);
    float lb = b - __uint_as_float(rb & 0xffff0000u);
    pl = __builtin_amdgcn_perm(__float_as_uint(lb) + 0x8000u,
                               __float_as_uint(la) + 0x8000u, 0x07060302u);
}

__device__ __forceinline__ short8 mk_short8(unsigned p0, unsigned p1,
                                            unsigned p2, unsigned p3) {
    union { unsigned u[4]; short8 s; } c;
    c.u[0] = p0; c.u[1] = p1; c.u[2] = p2; c.u[3] = p3;
    return c.s;
}

// Convert 8 consecutive fp32 (two float4) into hi/lo short8 fragments.
__device__ __forceinline__ void cvt_frag(const float* src,
                                         short8 &hi, short8 &lo) {
    float4 w0 = *(const float4*)src;
    float4 w1 = *(const float4*)(src + 4);
    unsigned ph[4], pl[4];
    split_pack(w0.x, w0.y, ph[0], pl[0]);
    split_pack(w0.z, w0.w, ph[1], pl[1]);
    split_pack(w1.x, w1.y, ph[2], pl[2]);
    split_pack(w1.z, w1.w, ph[3], pl[3]);
    hi = mk_short8(ph[0], ph[1], ph[2], ph[3]);
    lo = mk_short8(pl[0], pl[1], pl[2], pl[3]);
}

__device__ __forceinline__ float fast_exp2(float x) {
#if __has_builtin(__builtin_amdgcn_exp2f)
    return __builtin_amdgcn_exp2f(x);
#else
    return exp2f(x);
#endif
}

// ---------------------------------------------------------------------------
// QKV GEMM, region-merged -- EXACT round-10 form (proven 150.8 us run).
// Named accumulators acc0/acc1 (static indexing; runtime-indexed vector
// arrays spill to scratch -- measured round 9: 178 MB WRITE_SIZE).
// LDS 30720 B.  Grid (64 n, 3 region, 4 b), 256 threads.
// ---------------------------------------------------------------------------
__global__ __launch_bounds__(256) void gemm1_fused(
    const float* __restrict__ wq, const float* __restrict__ x,
    unsigned short* __restrict__ Qp, unsigned short* __restrict__ Kp,
    unsigned short* __restrict__ Vp)
{
    const int N = N_TOK;
    const int b = blockIdx.z;
    const int region = blockIdx.y;            // 0=Q, 1=K, 2=V
    const int col0 = blockIdx.x * 64;
    const int t = threadIdx.x;
    const int wave = t >> 6, lane = t & 63;
    const int l16 = lane & 15, quad = lane >> 4;
    const int msub0 = (wave & 1) * 32, nsub0 = (wave >> 1) * 32;

    // shorts: W0H@0, W0L@2560, W1H@5120, W1L@7680, XsH@10240, XsL@12800
    __shared__ __align__(16) char smem[30720];
    unsigned short* S = (unsigned short*)smem;

    floatx4 acc0[2][2] = {};   // sub 0 (rows region*128 ..  +63)
    floatx4 acc1[2][2] = {};   // sub 1 (rows region*128+64.. +127)

    const int wm = t >> 2, wk = (t & 3) * 8;       // W load role
    const int xn = t & 63, xc8 = (t >> 6) * 8;     // x transposed-load role

    for (int kc = 0; kc < 8; ++kc) {
        __syncthreads();
        {   // W sub-tile 0
            const float* wsrc = wq +
                (size_t)(region * 128 + wm) * 256 + kc * 32 + wk;
            float4 w0 = *(const float4*)wsrc;
            float4 w1 = *(const float4*)(wsrc + 4);
            unsigned ph[4], pl[4];
            split_pack(w0.x, w0.y, ph[0], pl[0]);
            split_pack(w0.z, w0.w, ph[1], pl[1]);
            split_pack(w1.x, w1.y, ph[2], pl[2]);
            split_pack(w1.z, w1.w, ph[3], pl[3]);
            *(uint4*)(S +        wm * 40 + wk) = *(uint4*)ph;
            *(uint4*)(S + 2560 + wm * 40 + wk) = *(uint4*)pl;
        }
        {   // W sub-tile 1
            const float* wsrc = wq +
                (size_t)(region * 128 + 64 + wm) * 256 + kc * 32 + wk;
            float4 w0 = *(const float4*)wsrc;
            float4 w1 = *(const float4*)(wsrc + 4);
            unsigned ph[4], pl[4];
            split_pack(w0.x, w0.y, ph[0], pl[0]);
            split_pack(w0.z, w0.w, ph[1], pl[1]);
            split_pack(w1.x, w1.y, ph[2], pl[2]);
            split_pack(w1.z, w1.w, ph[3], pl[3]);
            *(uint4*)(S + 5120 + wm * 40 + wk) = *(uint4*)ph;
            *(uint4*)(S + 7680 + wm * 40 + wk) = *(uint4*)pl;
        }
        {   // x chunk: transposed loads (coalesced in n) + split -> [n][40]
            const float* xsrc = x + ((size_t)b * 256 + kc * 32 + xc8) * N
                                  + col0 + xn;
            float v[8];
#pragma unroll
            for (int i = 0; i < 8; ++i) v[i] = xsrc[(size_t)i * N];
            unsigned ph[4], pl[4];
            split_pack(v[0], v[1], ph[0], pl[0]);
            split_pack(v[2], v[3], ph[1], pl[1]);
            split_pack(v[4], v[5], ph[2], pl[2]);
            split_pack(v[6], v[7], ph[3], pl[3]);
            *(uint4*)(S + 10240 + xn * 40 + xc8) = *(uint4*)ph;
            *(uint4*)(S + 12800 + xn * 40 + xc8) = *(uint4*)pl;
        }
        __syncthreads();
        // B fragments: loaded once, reused for both W subs
        short8 bh0 = *(const short8*)(S + 10240 + (nsub0 +      l16) * 40 + quad * 8);
        short8 bh1 = *(const short8*)(S + 10240 + (nsub0 + 16 + l16) * 40 + quad * 8);
        short8 bl0 = *(const short8*)(S + 12800 + (nsub0 +      l16) * 40 + quad * 8);
        short8 bl1 = *(const short8*)(S + 12800 + (nsub0 + 16 + l16) * 40 + quad * 8);

        auto mfma_sub = [&](floatx4 (&A)[2][2], const unsigned short* W0) {
            short8 ah0 = *(const short8*)(W0 +        (msub0 +      l16) * 40 + quad * 8);
            short8 ah1 = *(const short8*)(W0 +        (msub0 + 16 + l16) * 40 + quad * 8);
            short8 al0 = *(const short8*)(W0 + 2560 + (msub0 +      l16) * 40 + quad * 8);
            short8 al1 = *(const short8*)(W0 + 2560 + (msub0 + 16 + l16) * 40 + quad * 8);
            A[0][0] = __builtin_amdgcn_mfma_f32_16x16x32_bf16(ah0, bh0, A[0][0], 0, 0, 0);
            A[0][1] = __builtin_amdgcn_mfma_f32_16x16x32_bf16(ah0, bh1, A[0][1], 0, 0, 0);
            A[1][0] = __builtin_amdgcn_mfma_f32_16x16x32_bf16(ah1, bh0, A[1][0], 0, 0, 0);
            A[1][1] = __builtin_amdgcn_mfma_f32_16x16x32_bf16(ah1, bh1, A[1][1], 0, 0, 0);
            A[0][0] = __builtin_amdgcn_mfma_f32_16x16x32_bf16(ah0, bl0, A[0][0], 0, 0, 0);
            A[0][1] = __builtin_amdgcn_mfma_f32_16x16x32_bf16(ah0, bl1, A[0][1], 0, 0, 0);
            A[1][0] = __builtin_amdgcn_mfma_f32_16x16x32_bf16(ah1, bl0, A[1][0], 0, 0, 0);
            A[1][1] = __builtin_amdgcn_mfma_f32_16x16x32_bf16(ah1, bl1, A[1][1], 0, 0, 0);
            A[0][0] = __builtin_amdgcn_mfma_f32_16x16x32_bf16(al0, bh0, A[0][0], 0, 0, 0);
            A[0][1] = __builtin_amdgcn_mfma_f32_16x16x32_bf16(al0, bh1, A[0][1], 0, 0, 0);
            A[1][0] = __builtin_amdgcn_mfma_f32_16x16x32_bf16(al1, bh0, A[1][0], 0, 0, 0);
            A[1][1] = __builtin_amdgcn_mfma_f32_16x16x32_bf16(al1, bh1, A[1][1], 0, 0, 0);
        };
        mfma_sub(acc0, S);
        mfma_sub(acc1, S + 5120);
    }

    // ---- epilogue: two static passes of the proven 64-row epilogue ----
    auto epi = [&](floatx4 (&A)[2][2], const int row0) {
        __syncthreads();
        if (region == 2) {
            float (*LdsF)[68] = (float(*)[68])smem;
#pragma unroll
            for (int i = 0; i < 2; ++i)
#pragma unroll
                for (int j = 0; j < 2; ++j) {
                    const int m = msub0 + i * 16 + quad * 4;
                    const int n = nsub0 + j * 16 + l16;
#pragma unroll
                    for (int r = 0; r < 4; ++r) LdsF[m + r][n] = A[i][j][r];
                }
            __syncthreads();
            const int m = t >> 2, nb2 = (t & 3) * 16;
            const int vrow = b * 128 + (row0 - 256) + m;
            unsigned pk[8];
#pragma unroll
            for (int q = 0; q < 8; ++q)
                pk[q] = pack_rnd(LdsF[m][nb2 + 2 * q], LdsF[m][nb2 + 2 * q + 1]);
            unsigned short* dst = Vp + (size_t)vrow * N + col0 + nb2;
            *(uint4*)&dst[0] = *(uint4*)&pk[0];
            *(uint4*)&dst[8] = *(uint4*)&pk[4];
        } else {
            unsigned short (*LdsT)[68] = (unsigned short(*)[68])smem;
            const float sc = region ? 1.0f
                                    : (0.17677669529663687f * 1.4426950408889634f);
#pragma unroll
            for (int i = 0; i < 2; ++i)
#pragma unroll
                for (int j = 0; j < 2; ++j) {
                    const int m = msub0 + i * 16 + quad * 4;
                    const int n = nsub0 + j * 16 + l16;
                    uint2 pr;
                    pr.x = pack_rnd(A[i][j][0] * sc, A[i][j][1] * sc);
                    pr.y = pack_rnd(A[i][j][2] * sc, A[i][j][3] * sc);
                    *(uint2*)&LdsT[n][m] = pr;
                }
            __syncthreads();
            const int n = t & 63, hb = (t >> 6) & 1, dh = t >> 7;
            const int h = ((row0 & 127) >> 5) + hb;
            const int m0 = hb * 32 + dh * 16;
            unsigned tmp[8];
            *(uint2*)&tmp[0] = *(const uint2*)&LdsT[n][m0];
            *(uint2*)&tmp[2] = *(const uint2*)&LdsT[n][m0 + 4];
            *(uint2*)&tmp[4] = *(const uint2*)&LdsT[n][m0 + 8];
            *(uint2*)&tmp[6] = *(const uint2*)&LdsT[n][m0 + 12];
            unsigned short* dst = (region ? Kp : Qp) +
                ((size_t)(b * 4 + h) * N + col0 + n) * 32 + dh * 16;
            *(uint4*)&dst[0] = *(uint4*)&tmp[0];
            *(uint4*)&dst[8] = *(uint4*)&tmp[4];
        }
    };
    epi(acc0, region * 128);
    epi(acc1, region * 128 + 64);
}

// ---------------------------------------------------------------------------
// MFMA flash attention -- round-3 structure; THIS ROUND: the 16 P-path
// pack_rnd (3 VALU each) replaced by v_cvt_pk_bf16_f32 (1 VALU each, RNE).
// attn is VALU-bound (58% VALUBusy vs 30% MfmaUtil); saves 32 VALU/tile.
// Numerics: P rounding half-up -> RNE, <=1 ulp bf16 on ties only; absmax
// drifts a few e-6, must stay well under 1.1e-4.  All layouts unchanged.
// ---------------------------------------------------------------------------
__global__ __launch_bounds__(512) void attn_fused(
    const unsigned short* __restrict__ Qp,
    const unsigned short* __restrict__ Kp,
    const unsigned short* __restrict__ Vp,
    unsigned short* __restrict__ Oth, unsigned short* __restrict__ Otl)
{
    const int N = N_TOK;
    const int bh = blockIdx.y;
    const int b = bh >> 2, h = bh & 3;
    const int i0 = blockIdx.x * 128;
    const int t = threadIdx.x;
    const int wave = t >> 6, lane = t & 63;
    const int l16 = lane & 15, quad = lane >> 4;
    const int team = wave >> 2, w4 = wave & 3;

    __shared__ __align__(16) char smem[38912];
    unsigned short* S = (unsigned short*)smem;

    short8 ones;
#pragma unroll
    for (int e = 0; e < 8; ++e) ones[e] = (short)0x3F80;

    short8 qh[2];
#pragma unroll
    for (int g = 0; g < 2; ++g)
        qh[g] = *(const short8*)(Qp +
            ((size_t)bh * N + i0 + w4 * 32 + g * 16 + l16) * 32 + quad * 8);

    floatx4 o[2][2] = {};
    floatx4 lacc[2] = {};

    const int st_k = t & 255;
    const int skey = st_k >> 2, sdp = (st_k & 3) * 8;
    const int sslot = (skey & 32) | ((skey & 4) << 2) | ((skey & 24) >> 1)
                    | (skey & 3);
    const int svd = st_k >> 3, svp = (st_k & 7) * 8;
    const unsigned short* kp0 = Kp + ((size_t)bh * N + skey) * 32 + sdp;
    const unsigned short* kp1 = kp0 + (size_t)2048 * 32;
    const unsigned short* vp0 = Vp + ((size_t)bh * 32 + svd) * N + svp;
    const unsigned short* vp1 = vp0 + 2048;

    short8 r0, r1;
    if (t < 256) { r0 = *(const short8*)kp0; r1 = *(const short8*)kp1; }
    else         { r0 = *(const short8*)vp0; r1 = *(const short8*)vp1; }
    if (t < 256) {
        *(short8*)(S + sslot * 40 + sdp) = r0;
        *(short8*)(S + 2560 + sslot * 40 + sdp) = r1;
    } else {
        *(short8*)(S + 10240 + svd * 72 + svp) = r0;
        *(short8*)(S + 10240 + 2304 + svd * 72 + svp) = r1;
    }
    kp0 += 64 * 32; kp1 += 64 * 32; vp0 += 64; vp1 += 64;
    if (t < 256) { r0 = *(const short8*)kp0; r1 = *(const short8*)kp1; }
    else         { r0 = *(const short8*)vp0; r1 = *(const short8*)vp1; }
    __syncthreads();

    for (int it = 0; it < 32; ++it) {
        const int cur = it & 1;
        if (it + 1 < 32) {
            const int nb = 1 - cur;
            if (t < 256) {
                *(short8*)(S + nb * 5120 + sslot * 40 + sdp) = r0;
                *(short8*)(S + nb * 5120 + 2560 + sslot * 40 + sdp) = r1;
            } else {
                *(short8*)(S + 10240 + nb * 4608 + svd * 72 + svp) = r0;
                *(short8*)(S + 10240 + nb * 4608 + 2304 + svd * 72 + svp) = r1;
            }
        }
        if (it + 2 < 32) {
            kp0 += 64 * 32; kp1 += 64 * 32; vp0 += 64; vp1 += 64;
            if (t < 256) { r0 = *(const short8*)kp0; r1 = *(const short8*)kp1; }
            else         { r0 = *(const short8*)vp0; r1 = *(const short8*)vp1; }
        }

        const unsigned short* Ksr = S + cur * 5120 + team * 2560;
        const unsigned short* Vsr = S + 10240 + cur * 4608 + team * 2304;

        short8 kh0 = *(const short8*)(Ksr + ( 0 + l16) * 40 + quad * 8);
        short8 kh1 = *(const short8*)(Ksr + (16 + l16) * 40 + quad * 8);
        short8 kh2 = *(const short8*)(Ksr + (32 + l16) * 40 + quad * 8);
        short8 kh3 = *(const short8*)(Ksr + (48 + l16) * 40 + quad * 8);
        short8 vh00 = *(const short8*)(Vsr + ( 0 + l16) * 72 +  0 + quad * 8);
        short8 vh01 = *(const short8*)(Vsr + (16 + l16) * 72 +  0 + quad * 8);
        short8 vh10 = *(const short8*)(Vsr + ( 0 + l16) * 72 + 32 + quad * 8);
        short8 vh11 = *(const short8*)(Vsr + (16 + l16) * 72 + 32 + quad * 8);

#pragma unroll
        for (int g = 0; g < 2; ++g) {
            const floatx4 z = {0.0f, 0.0f, 0.0f, 0.0f};
            floatx4 s0 = __builtin_amdgcn_mfma_f32_16x16x32_bf16(kh0, qh[g], z, 0, 0, 0);
            floatx4 s1 = __builtin_amdgcn_mfma_f32_16x16x32_bf16(kh1, qh[g], z, 0, 0, 0);
            floatx4 s2 = __builtin_amdgcn_mfma_f32_16x16x32_bf16(kh2, qh[g], z, 0, 0, 0);
            floatx4 s3 = __builtin_amdgcn_mfma_f32_16x16x32_bf16(kh3, qh[g], z, 0, 0, 0);
            short8 pf0 = mk_short8(
                cvt_pk_bf16(fast_exp2(s0[0]), fast_exp2(s0[1])),
                cvt_pk_bf16(fast_exp2(s0[2]), fast_exp2(s0[3])),
                cvt_pk_bf16(fast_exp2(s1[0]), fast_exp2(s1[1])),
                cvt_pk_bf16(fast_exp2(s1[2]), fast_exp2(s1[3])));
            o[g][0] = __builtin_amdgcn_mfma_f32_16x16x32_bf16(vh00, pf0, o[g][0], 0, 0, 0);
            o[g][1] = __builtin_amdgcn_mfma_f32_16x16x32_bf16(vh01, pf0, o[g][1], 0, 0, 0);
            lacc[g] = __builtin_amdgcn_mfma_f32_16x16x32_bf16(ones, pf0, lacc[g], 0, 0, 0);
            short8 pf1 = mk_short8(
                cvt_pk_bf16(fast_exp2(s2[0]), fast_exp2(s2[1])),
                cvt_pk_bf16(fast_exp2(s2[2]), fast_exp2(s2[3])),
                cvt_pk_bf16(fast_exp2(s3[0]), fast_exp2(s3[1])),
                cvt_pk_bf16(fast_exp2(s3[2]), fast_exp2(s3[3])));
            o[g][0] = __builtin_amdgcn_mfma_f32_16x16x32_bf16(vh10, pf1, o[g][0], 0, 0, 0);
            o[g][1] = __builtin_amdgcn_mfma_f32_16x16x32_bf16(vh11, pf1, o[g][1], 0, 0, 0);
            lacc[g] = __builtin_amdgcn_mfma_f32_16x16x32_bf16(ones, pf1, lacc[g], 0, 0, 0);
        }
        __syncthreads();
    }

    float (*OfB)[132] = (float(*)[132])smem;
    float* Lb = (float*)(smem + 16896);
    float (*OfA)[132] = (float(*)[132])(smem + 17408);

    if (team == 1) {
#pragma unroll
        for (int g = 0; g < 2; ++g) {
            const int q = w4 * 32 + g * 16 + l16;
#pragma unroll
            for (int half = 0; half < 2; ++half)
#pragma unroll
                for (int r = 0; r < 4; ++r)
                    OfB[half * 16 + quad * 4 + r][q] = o[g][half][r];
            if (quad == 0) Lb[q] = lacc[g][0];
        }
    }
    __syncthreads();
    if (team == 0) {
#pragma unroll
        for (int g = 0; g < 2; ++g) {
            const int q = w4 * 32 + g * 16 + l16;
            const float inv = 1.0f / (lacc[g][0] + Lb[q]);
#pragma unroll
            for (int half = 0; half < 2; ++half)
#pragma unroll
                for (int r = 0; r < 4; ++r) {
                    const int d = half * 16 + quad * 4 + r;
                    OfA[d][q] = (o[g][half][r] + OfB[d][q]) * inv;
                }
        }
    }
    __syncthreads();
    {
        const int q = t >> 2, db = (t & 3) * 8;
        unsigned ph[4], pl[4];
#pragma unroll
        for (int i = 0; i < 4; ++i)
            split_pack(OfA[db + 2 * i][q], OfA[db + 2 * i + 1][q], ph[i], pl[i]);
        const size_t off = ((size_t)b * N + i0 + q) * 128 + h * 32 + db;
        *(uint4*)(Oth + off) = *(uint4*)ph;
        *(uint4*)(Otl + off) = *(uint4*)pl;
    }
}

// ---------------------------------------------------------------------------
// Output GEMM -- EXACT round-3/6 form (proven).  Grid (64 n, 4 m, 4 b).
// ---------------------------------------------------------------------------
__global__ __launch_bounds__(256) void gemm2_fused(
    const float* __restrict__ wo,
    const unsigned short* __restrict__ Oth, const unsigned short* __restrict__ Otl,
    const float* __restrict__ bias, float* __restrict__ y)
{
    const int N = N_TOK;
    const int b = blockIdx.z;
    const int row0 = blockIdx.y * 64;
    const int col0 = blockIdx.x * 64;
    const int t = threadIdx.x;
    const int wave = t >> 6, lane = t & 63;
    const int l16 = lane & 15, quad = lane >> 4;
    const int msub0 = (wave & 1) * 32, nsub0 = (wave >> 1) * 32;

    __shared__ __align__(16) char smem[17408];
    unsigned short* BsH = (unsigned short*)smem;           // [64][40]
    unsigned short* BsL = (unsigned short*)(smem + 5120);  // [64][40]
    float (*LdsF)[68] = (float(*)[68])smem;                // epilogue reuse

    short8 ah[4][2], al[4][2];
#pragma unroll
    for (int kc = 0; kc < 4; ++kc)
#pragma unroll
        for (int r = 0; r < 2; ++r)
            cvt_frag(wo + (size_t)(row0 + msub0 + r * 16 + l16) * 128 +
                         kc * 32 + quad * 8,
                     ah[kc][r], al[kc][r]);

    const int srow = t >> 2, sk = (t & 3) * 8;
    const unsigned short* gH = Oth + ((size_t)b * N + col0 + srow) * 128 + sk;
    const unsigned short* gL = Otl + ((size_t)b * N + col0 + srow) * 128 + sk;

    floatx4 acc[2][2] = {};
#pragma unroll
    for (int kc = 0; kc < 4; ++kc) {
        short8 hreg = *(const short8*)(gH + kc * 32);
        short8 lreg = *(const short8*)(gL + kc * 32);
        __syncthreads();
        *(short8*)(BsH + srow * 40 + sk) = hreg;
        *(short8*)(BsL + srow * 40 + sk) = lreg;
        __syncthreads();
        short8 bh0 = *(const short8*)(BsH + (nsub0 + l16) * 40 + quad * 8);
        short8 bh1 = *(const short8*)(BsH + (nsub0 + 16 + l16) * 40 + quad * 8);
        short8 bl0 = *(const short8*)(BsL + (nsub0 + l16) * 40 + quad * 8);
        short8 bl1 = *(const short8*)(BsL + (nsub0 + 16 + l16) * 40 + quad * 8);
        acc[0][0] = __builtin_amdgcn_mfma_f32_16x16x32_bf16(ah[kc][0], bh0, acc[0][0], 0, 0, 0);
        acc[0][1] = __builtin_amdgcn_mfma_f32_16x16x32_bf16(ah[kc][0], bh1, acc[0][1], 0, 0, 0);
        acc[1][0] = __builtin_amdgcn_mfma_f32_16x16x32_bf16(ah[kc][1], bh0, acc[1][0], 0, 0, 0);
        acc[1][1] = __builtin_amdgcn_mfma_f32_16x16x32_bf16(ah[kc][1], bh1, acc[1][1], 0, 0, 0);
        acc[0][0] = __builtin_amdgcn_mfma_f32_16x16x32_bf16(ah[kc][0], bl0, acc[0][0], 0, 0, 0);
        acc[0][1] = __builtin_amdgcn_mfma_f32_16x16x32_bf16(ah[kc][0], bl1, acc[0][1], 0, 0, 0);
        acc[1][0] = __builtin_amdgcn_mfma_f32_16x16x32_bf16(ah[kc][1], bl0, acc[1][0], 0, 0, 0);
        acc[1][1] = __builtin_amdgcn_mfma_f32_16x16x32_bf16(ah[kc][1], bl1, acc[1][1], 0, 0, 0);
        acc[0][0] = __builtin_amdgcn_mfma_f32_16x16x32_bf16(al[kc][0], bh0, acc[0][0], 0, 0, 0);
        acc[0][1] = __builtin_amdgcn_mfma_f32_16x16x32_bf16(al[kc][0], bh1, acc[0][1], 0, 0, 0);
        acc[1][0] = __builtin_amdgcn_mfma_f32_16x16x32_bf16(al[kc][1], bh0, acc[1][0], 0, 0, 0);
        acc[1][1] = __builtin_amdgcn_mfma_f32_16x16x32_bf16(al[kc][1], bh1, acc[1][1], 0, 0, 0);
    }

    __syncthreads();
#pragma unroll
    for (int i = 0; i < 2; ++i)
#pragma unroll
        for (int j = 0; j < 2; ++j) {
            const int m = msub0 + i * 16 + quad * 4;
            const int n = nsub0 + j * 16 + l16;
#pragma unroll
            for (int r = 0; r < 4; ++r) LdsF[m + r][n] = acc[i][j][r];
        }
    __syncthreads();
    const int m = t >> 2, nb = (t & 3) * 16;
    const float bv = bias[row0 + m];
    float* dst = y + ((size_t)b * 256 + row0 + m) * N + col0 + nb;
#pragma unroll
    for (int g = 0; g < 4; ++g) {
        float4 o4;
        o4.x = LdsF[m][nb + g * 4 + 0] + bv;
        o4.y = LdsF[m][nb + g * 4 + 1] + bv;
        o4.z = LdsF[m][nb + g * 4 + 2] + bv;
        o4.w = LdsF[m][nb + g * 4 + 3] + bv;
        *(float4*)(dst + g * 4) = o4;
    }
}

extern "C" void kernel_launch(void* const* d_in, const int* in_sizes, int n_in,
                              void* d_out, int out_size, void* d_ws, size_t ws_size,
                              hipStream_t stream) {
    const float* x     = (const float*)d_in[0];
    const float* w_qkv = (const float*)d_in[1];
    const float* w_out = (const float*)d_in[2];
    const float* b_out = (const float*)d_in[3];
    float* y = (float*)d_out;

    // workspace 20 MiB: Qp, Kp, Vp, Oth, Otl (4 MiB each)
    char* base = (char*)d_ws;
    unsigned short* Qp  = (unsigned short*)base;
    unsigned short* Kp  = Qp + (size_t)16 * N_TOK * 32;
    unsigned short* Vp  = Kp + (size_t)16 * N_TOK * 32;
    unsigned short* Oth = Vp + (size_t)16 * N_TOK * 32;
    unsigned short* Otl = Oth + (size_t)BATCH * N_TOK * 128;

    gemm1_fused<<<dim3(64, 3, BATCH), dim3(256), 0, stream>>>(
        w_qkv, x, Qp, Kp, Vp);
    attn_fused<<<dim3(32, 16), dim3(512), 0, stream>>>(Qp, Kp, Vp, Oth, Otl);
    gemm2_fused<<<dim3(64, 4, BATCH), dim3(256), 0, stream>>>(
        w_out, Oth, Otl, b_out, y);
}

// Round 12
// 143.915 us; speedup vs baseline: 1.4125x; 1.0354x over previous
//
#include <hip/hip_runtime.h>

#define N_TOK 4096
#define BATCH 4

typedef __attribute__((ext_vector_type(8))) short short8;
typedef __attribute__((ext_vector_type(4))) float floatx4;

// Pack two floats to packed bf16 (RNE) in ONE VALU instruction.
// Convention: D.lo = bf16(a), D.hi = bf16(b)  (verified vs pack_rnd, r11).
__device__ __forceinline__ unsigned cvt_pk_bf16(float a, float b) {
    unsigned d;
    asm("v_cvt_pk_bf16_f32 %0, %1, %2" : "=v"(d) : "v"(a), "v"(b));
    return d;
}

// Split two floats into bf16 hi-pair and lo-pair: 6 VALU (was 11).
// hi = RNE(a),RNE(b); lo = RNE(a-hi_a), RNE(b-hi_b).  Exact f32 residual.
__device__ __forceinline__ void split_pack(float a, float b,
                                           unsigned &ph, unsigned &pl) {
    ph = cvt_pk_bf16(a, b);
    float ha = __uint_as_float(ph << 16);           // bf16(a) as f32
    float hb = __uint_as_float(ph & 0xffff0000u);   // bf16(b) as f32
    pl = cvt_pk_bf16(a - ha, b - hb);
}

__device__ __forceinline__ short8 mk_short8(unsigned p0, unsigned p1,
                                            unsigned p2, unsigned p3) {
    union { unsigned u[4]; short8 s; } c;
    c.u[0] = p0; c.u[1] = p1; c.u[2] = p2; c.u[3] = p3;
    return c.s;
}

// Convert 8 consecutive fp32 (two float4) into hi/lo short8 fragments.
__device__ __forceinline__ void cvt_frag(const float* src,
                                         short8 &hi, short8 &lo) {
    float4 w0 = *(const float4*)src;
    float4 w1 = *(const float4*)(src + 4);
    unsigned ph[4], pl[4];
    split_pack(w0.x, w0.y, ph[0], pl[0]);
    split_pack(w0.z, w0.w, ph[1], pl[1]);
    split_pack(w1.x, w1.y, ph[2], pl[2]);
    split_pack(w1.z, w1.w, ph[3], pl[3]);
    hi = mk_short8(ph[0], ph[1], ph[2], ph[3]);
    lo = mk_short8(pl[0], pl[1], pl[2], pl[3]);
}

__device__ __forceinline__ float fast_exp2(float x) {
#if __has_builtin(__builtin_amdgcn_exp2f)
    return __builtin_amdgcn_exp2f(x);
#else
    return exp2f(x);
#endif
}

// ---------------------------------------------------------------------------
// QKV GEMM, region-merged (round-10 structure, proven).  THIS ROUND: all
// conversions use the 1-instr v_cvt_pk_bf16_f32 (split 11->6 VALU/pair,
// pack 3->1).  gemm1 is staging-VALU-bound per-wave (~265 VALU cyc vs ~120
// MFMA cyc per kc); this cuts the staging critical path ~40%.
// Named accumulators (static indexing -- r9 spill lesson).
// LDS 30720 B.  Grid (64 n, 3 region, 4 b), 256 threads.
// ---------------------------------------------------------------------------
__global__ __launch_bounds__(256) void gemm1_fused(
    const float* __restrict__ wq, const float* __restrict__ x,
    unsigned short* __restrict__ Qp, unsigned short* __restrict__ Kp,
    unsigned short* __restrict__ Vp)
{
    const int N = N_TOK;
    const int b = blockIdx.z;
    const int region = blockIdx.y;            // 0=Q, 1=K, 2=V
    const int col0 = blockIdx.x * 64;
    const int t = threadIdx.x;
    const int wave = t >> 6, lane = t & 63;
    const int l16 = lane & 15, quad = lane >> 4;
    const int msub0 = (wave & 1) * 32, nsub0 = (wave >> 1) * 32;

    // shorts: W0H@0, W0L@2560, W1H@5120, W1L@7680, XsH@10240, XsL@12800
    __shared__ __align__(16) char smem[30720];
    unsigned short* S = (unsigned short*)smem;

    floatx4 acc0[2][2] = {};   // sub 0 (rows region*128 ..  +63)
    floatx4 acc1[2][2] = {};   // sub 1 (rows region*128+64.. +127)

    const int wm = t >> 2, wk = (t & 3) * 8;       // W load role
    const int xn = t & 63, xc8 = (t >> 6) * 8;     // x transposed-load role

    for (int kc = 0; kc < 8; ++kc) {
        __syncthreads();
        {   // W sub-tile 0
            const float* wsrc = wq +
                (size_t)(region * 128 + wm) * 256 + kc * 32 + wk;
            float4 w0 = *(const float4*)wsrc;
            float4 w1 = *(const float4*)(wsrc + 4);
            unsigned ph[4], pl[4];
            split_pack(w0.x, w0.y, ph[0], pl[0]);
            split_pack(w0.z, w0.w, ph[1], pl[1]);
            split_pack(w1.x, w1.y, ph[2], pl[2]);
            split_pack(w1.z, w1.w, ph[3], pl[3]);
            *(uint4*)(S +        wm * 40 + wk) = *(uint4*)ph;
            *(uint4*)(S + 2560 + wm * 40 + wk) = *(uint4*)pl;
        }
        {   // W sub-tile 1
            const float* wsrc = wq +
                (size_t)(region * 128 + 64 + wm) * 256 + kc * 32 + wk;
            float4 w0 = *(const float4*)wsrc;
            float4 w1 = *(const float4*)(wsrc + 4);
            unsigned ph[4], pl[4];
            split_pack(w0.x, w0.y, ph[0], pl[0]);
            split_pack(w0.z, w0.w, ph[1], pl[1]);
            split_pack(w1.x, w1.y, ph[2], pl[2]);
            split_pack(w1.z, w1.w, ph[3], pl[3]);
            *(uint4*)(S + 5120 + wm * 40 + wk) = *(uint4*)ph;
            *(uint4*)(S + 7680 + wm * 40 + wk) = *(uint4*)pl;
        }
        {   // x chunk: transposed loads (coalesced in n) + split -> [n][40]
            const float* xsrc = x + ((size_t)b * 256 + kc * 32 + xc8) * N
                                  + col0 + xn;
            float v[8];
#pragma unroll
            for (int i = 0; i < 8; ++i) v[i] = xsrc[(size_t)i * N];
            unsigned ph[4], pl[4];
            split_pack(v[0], v[1], ph[0], pl[0]);
            split_pack(v[2], v[3], ph[1], pl[1]);
            split_pack(v[4], v[5], ph[2], pl[2]);
            split_pack(v[6], v[7], ph[3], pl[3]);
            *(uint4*)(S + 10240 + xn * 40 + xc8) = *(uint4*)ph;
            *(uint4*)(S + 12800 + xn * 40 + xc8) = *(uint4*)pl;
        }
        __syncthreads();
        // B fragments: loaded once, reused for both W subs
        short8 bh0 = *(const short8*)(S + 10240 + (nsub0 +      l16) * 40 + quad * 8);
        short8 bh1 = *(const short8*)(S + 10240 + (nsub0 + 16 + l16) * 40 + quad * 8);
        short8 bl0 = *(const short8*)(S + 12800 + (nsub0 +      l16) * 40 + quad * 8);
        short8 bl1 = *(const short8*)(S + 12800 + (nsub0 + 16 + l16) * 40 + quad * 8);

        auto mfma_sub = [&](floatx4 (&A)[2][2], const unsigned short* W0) {
            short8 ah0 = *(const short8*)(W0 +        (msub0 +      l16) * 40 + quad * 8);
            short8 ah1 = *(const short8*)(W0 +        (msub0 + 16 + l16) * 40 + quad * 8);
            short8 al0 = *(const short8*)(W0 + 2560 + (msub0 +      l16) * 40 + quad * 8);
            short8 al1 = *(const short8*)(W0 + 2560 + (msub0 + 16 + l16) * 40 + quad * 8);
            A[0][0] = __builtin_amdgcn_mfma_f32_16x16x32_bf16(ah0, bh0, A[0][0], 0, 0, 0);
            A[0][1] = __builtin_amdgcn_mfma_f32_16x16x32_bf16(ah0, bh1, A[0][1], 0, 0, 0);
            A[1][0] = __builtin_amdgcn_mfma_f32_16x16x32_bf16(ah1, bh0, A[1][0], 0, 0, 0);
            A[1][1] = __builtin_amdgcn_mfma_f32_16x16x32_bf16(ah1, bh1, A[1][1], 0, 0, 0);
            A[0][0] = __builtin_amdgcn_mfma_f32_16x16x32_bf16(ah0, bl0, A[0][0], 0, 0, 0);
            A[0][1] = __builtin_amdgcn_mfma_f32_16x16x32_bf16(ah0, bl1, A[0][1], 0, 0, 0);
            A[1][0] = __builtin_amdgcn_mfma_f32_16x16x32_bf16(ah1, bl0, A[1][0], 0, 0, 0);
            A[1][1] = __builtin_amdgcn_mfma_f32_16x16x32_bf16(ah1, bl1, A[1][1], 0, 0, 0);
            A[0][0] = __builtin_amdgcn_mfma_f32_16x16x32_bf16(al0, bh0, A[0][0], 0, 0, 0);
            A[0][1] = __builtin_amdgcn_mfma_f32_16x16x32_bf16(al0, bh1, A[0][1], 0, 0, 0);
            A[1][0] = __builtin_amdgcn_mfma_f32_16x16x32_bf16(al1, bh0, A[1][0], 0, 0, 0);
            A[1][1] = __builtin_amdgcn_mfma_f32_16x16x32_bf16(al1, bh1, A[1][1], 0, 0, 0);
        };
        mfma_sub(acc0, S);
        mfma_sub(acc1, S + 5120);
    }

    // ---- epilogue: two static passes of the proven 64-row epilogue ----
    auto epi = [&](floatx4 (&A)[2][2], const int row0) {
        __syncthreads();
        if (region == 2) {
            float (*LdsF)[68] = (float(*)[68])smem;
#pragma unroll
            for (int i = 0; i < 2; ++i)
#pragma unroll
                for (int j = 0; j < 2; ++j) {
                    const int m = msub0 + i * 16 + quad * 4;
                    const int n = nsub0 + j * 16 + l16;
#pragma unroll
                    for (int r = 0; r < 4; ++r) LdsF[m + r][n] = A[i][j][r];
                }
            __syncthreads();
            const int m = t >> 2, nb2 = (t & 3) * 16;
            const int vrow = b * 128 + (row0 - 256) + m;
            unsigned pk[8];
#pragma unroll
            for (int q = 0; q < 8; ++q)
                pk[q] = cvt_pk_bf16(LdsF[m][nb2 + 2 * q], LdsF[m][nb2 + 2 * q + 1]);
            unsigned short* dst = Vp + (size_t)vrow * N + col0 + nb2;
            *(uint4*)&dst[0] = *(uint4*)&pk[0];
            *(uint4*)&dst[8] = *(uint4*)&pk[4];
        } else {
            unsigned short (*LdsT)[68] = (unsigned short(*)[68])smem;
            const float sc = region ? 1.0f
                                    : (0.17677669529663687f * 1.4426950408889634f);
#pragma unroll
            for (int i = 0; i < 2; ++i)
#pragma unroll
                for (int j = 0; j < 2; ++j) {
                    const int m = msub0 + i * 16 + quad * 4;
                    const int n = nsub0 + j * 16 + l16;
                    uint2 pr;
                    pr.x = cvt_pk_bf16(A[i][j][0] * sc, A[i][j][1] * sc);
                    pr.y = cvt_pk_bf16(A[i][j][2] * sc, A[i][j][3] * sc);
                    *(uint2*)&LdsT[n][m] = pr;
                }
            __syncthreads();
            const int n = t & 63, hb = (t >> 6) & 1, dh = t >> 7;
            const int h = ((row0 & 127) >> 5) + hb;
            const int m0 = hb * 32 + dh * 16;
            unsigned tmp[8];
            *(uint2*)&tmp[0] = *(const uint2*)&LdsT[n][m0];
            *(uint2*)&tmp[2] = *(const uint2*)&LdsT[n][m0 + 4];
            *(uint2*)&tmp[4] = *(const uint2*)&LdsT[n][m0 + 8];
            *(uint2*)&tmp[6] = *(const uint2*)&LdsT[n][m0 + 12];
            unsigned short* dst = (region ? Kp : Qp) +
                ((size_t)(b * 4 + h) * N + col0 + n) * 32 + dh * 16;
            *(uint4*)&dst[0] = *(uint4*)&tmp[0];
            *(uint4*)&dst[8] = *(uint4*)&tmp[4];
        }
    };
    epi(acc0, region * 128);
    epi(acc1, region * 128 + 64);
}

// ---------------------------------------------------------------------------
// MFMA flash attention -- round-11 form (proven 51.2 us): cvt_pk P-path.
// THIS ROUND: epilogue split_pack also uses the fast cvt_pk split.
// ---------------------------------------------------------------------------
__global__ __launch_bounds__(512) void attn_fused(
    const unsigned short* __restrict__ Qp,
    const unsigned short* __restrict__ Kp,
    const unsigned short* __restrict__ Vp,
    unsigned short* __restrict__ Oth, unsigned short* __restrict__ Otl)
{
    const int N = N_TOK;
    const int bh = blockIdx.y;
    const int b = bh >> 2, h = bh & 3;
    const int i0 = blockIdx.x * 128;
    const int t = threadIdx.x;
    const int wave = t >> 6, lane = t & 63;
    const int l16 = lane & 15, quad = lane >> 4;
    const int team = wave >> 2, w4 = wave & 3;

    __shared__ __align__(16) char smem[38912];
    unsigned short* S = (unsigned short*)smem;

    short8 ones;
#pragma unroll
    for (int e = 0; e < 8; ++e) ones[e] = (short)0x3F80;

    short8 qh[2];
#pragma unroll
    for (int g = 0; g < 2; ++g)
        qh[g] = *(const short8*)(Qp +
            ((size_t)bh * N + i0 + w4 * 32 + g * 16 + l16) * 32 + quad * 8);

    floatx4 o[2][2] = {};
    floatx4 lacc[2] = {};

    const int st_k = t & 255;
    const int skey = st_k >> 2, sdp = (st_k & 3) * 8;
    const int sslot = (skey & 32) | ((skey & 4) << 2) | ((skey & 24) >> 1)
                    | (skey & 3);
    const int svd = st_k >> 3, svp = (st_k & 7) * 8;
    const unsigned short* kp0 = Kp + ((size_t)bh * N + skey) * 32 + sdp;
    const unsigned short* kp1 = kp0 + (size_t)2048 * 32;
    const unsigned short* vp0 = Vp + ((size_t)bh * 32 + svd) * N + svp;
    const unsigned short* vp1 = vp0 + 2048;

    short8 r0, r1;
    if (t < 256) { r0 = *(const short8*)kp0; r1 = *(const short8*)kp1; }
    else         { r0 = *(const short8*)vp0; r1 = *(const short8*)vp1; }
    if (t < 256) {
        *(short8*)(S + sslot * 40 + sdp) = r0;
        *(short8*)(S + 2560 + sslot * 40 + sdp) = r1;
    } else {
        *(short8*)(S + 10240 + svd * 72 + svp) = r0;
        *(short8*)(S + 10240 + 2304 + svd * 72 + svp) = r1;
    }
    kp0 += 64 * 32; kp1 += 64 * 32; vp0 += 64; vp1 += 64;
    if (t < 256) { r0 = *(const short8*)kp0; r1 = *(const short8*)kp1; }
    else         { r0 = *(const short8*)vp0; r1 = *(const short8*)vp1; }
    __syncthreads();

    for (int it = 0; it < 32; ++it) {
        const int cur = it & 1;
        if (it + 1 < 32) {
            const int nb = 1 - cur;
            if (t < 256) {
                *(short8*)(S + nb * 5120 + sslot * 40 + sdp) = r0;
                *(short8*)(S + nb * 5120 + 2560 + sslot * 40 + sdp) = r1;
            } else {
                *(short8*)(S + 10240 + nb * 4608 + svd * 72 + svp) = r0;
                *(short8*)(S + 10240 + nb * 4608 + 2304 + svd * 72 + svp) = r1;
            }
        }
        if (it + 2 < 32) {
            kp0 += 64 * 32; kp1 += 64 * 32; vp0 += 64; vp1 += 64;
            if (t < 256) { r0 = *(const short8*)kp0; r1 = *(const short8*)kp1; }
            else         { r0 = *(const short8*)vp0; r1 = *(const short8*)vp1; }
        }

        const unsigned short* Ksr = S + cur * 5120 + team * 2560;
        const unsigned short* Vsr = S + 10240 + cur * 4608 + team * 2304;

        short8 kh0 = *(const short8*)(Ksr + ( 0 + l16) * 40 + quad * 8);
        short8 kh1 = *(const short8*)(Ksr + (16 + l16) * 40 + quad * 8);
        short8 kh2 = *(const short8*)(Ksr + (32 + l16) * 40 + quad * 8);
        short8 kh3 = *(const short8*)(Ksr + (48 + l16) * 40 + quad * 8);
        short8 vh00 = *(const short8*)(Vsr + ( 0 + l16) * 72 +  0 + quad * 8);
        short8 vh01 = *(const short8*)(Vsr + (16 + l16) * 72 +  0 + quad * 8);
        short8 vh10 = *(const short8*)(Vsr + ( 0 + l16) * 72 + 32 + quad * 8);
        short8 vh11 = *(const short8*)(Vsr + (16 + l16) * 72 + 32 + quad * 8);

#pragma unroll
        for (int g = 0; g < 2; ++g) {
            const floatx4 z = {0.0f, 0.0f, 0.0f, 0.0f};
            floatx4 s0 = __builtin_amdgcn_mfma_f32_16x16x32_bf16(kh0, qh[g], z, 0, 0, 0);
            floatx4 s1 = __builtin_amdgcn_mfma_f32_16x16x32_bf16(kh1, qh[g], z, 0, 0, 0);
            floatx4 s2 = __builtin_amdgcn_mfma_f32_16x16x32_bf16(kh2, qh[g], z, 0, 0, 0);
            floatx4 s3 = __builtin_amdgcn_mfma_f32_16x16x32_bf16(kh3, qh[g], z, 0, 0, 0);
            short8 pf0 = mk_short8(
                cvt_pk_bf16(fast_exp2(s0[0]), fast_exp2(s0[1])),
                cvt_pk_bf16(fast_exp2(s0[2]), fast_exp2(s0[3])),
                cvt_pk_bf16(fast_exp2(s1[0]), fast_exp2(s1[1])),
                cvt_pk_bf16(fast_exp2(s1[2]), fast_exp2(s1[3])));
            o[g][0] = __builtin_amdgcn_mfma_f32_16x16x32_bf16(vh00, pf0, o[g][0], 0, 0, 0);
            o[g][1] = __builtin_amdgcn_mfma_f32_16x16x32_bf16(vh01, pf0, o[g][1], 0, 0, 0);
            lacc[g] = __builtin_amdgcn_mfma_f32_16x16x32_bf16(ones, pf0, lacc[g], 0, 0, 0);
            short8 pf1 = mk_short8(
                cvt_pk_bf16(fast_exp2(s2[0]), fast_exp2(s2[1])),
                cvt_pk_bf16(fast_exp2(s2[2]), fast_exp2(s2[3])),
                cvt_pk_bf16(fast_exp2(s3[0]), fast_exp2(s3[1])),
                cvt_pk_bf16(fast_exp2(s3[2]), fast_exp2(s3[3])));
            o[g][0] = __builtin_amdgcn_mfma_f32_16x16x32_bf16(vh10, pf1, o[g][0], 0, 0, 0);
            o[g][1] = __builtin_amdgcn_mfma_f32_16x16x32_bf16(vh11, pf1, o[g][1], 0, 0, 0);
            lacc[g] = __builtin_amdgcn_mfma_f32_16x16x32_bf16(ones, pf1, lacc[g], 0, 0, 0);
        }
        __syncthreads();
    }

    float (*OfB)[132] = (float(*)[132])smem;
    float* Lb = (float*)(smem + 16896);
    float (*OfA)[132] = (float(*)[132])(smem + 17408);

    if (team == 1) {
#pragma unroll
        for (int g = 0; g < 2; ++g) {
            const int q = w4 * 32 + g * 16 + l16;
#pragma unroll
            for (int half = 0; half < 2; ++half)
#pragma unroll
                for (int r = 0; r < 4; ++r)
                    OfB[half * 16 + quad * 4 + r][q] = o[g][half][r];
            if (quad == 0) Lb[q] = lacc[g][0];
        }
    }
    __syncthreads();
    if (team == 0) {
#pragma unroll
        for (int g = 0; g < 2; ++g) {
            const int q = w4 * 32 + g * 16 + l16;
            const float inv = 1.0f / (lacc[g][0] + Lb[q]);
#pragma unroll
            for (int half = 0; half < 2; ++half)
#pragma unroll
                for (int r = 0; r < 4; ++r) {
                    const int d = half * 16 + quad * 4 + r;
                    OfA[d][q] = (o[g][half][r] + OfB[d][q]) * inv;
                }
        }
    }
    __syncthreads();
    {
        const int q = t >> 2, db = (t & 3) * 8;
        unsigned ph[4], pl[4];
#pragma unroll
        for (int i = 0; i < 4; ++i)
            split_pack(OfA[db + 2 * i][q], OfA[db + 2 * i + 1][q], ph[i], pl[i]);
        const size_t off = ((size_t)b * N + i0 + q) * 128 + h * 32 + db;
        *(uint4*)(Oth + off) = *(uint4*)ph;
        *(uint4*)(Otl + off) = *(uint4*)pl;
    }
}

// ---------------------------------------------------------------------------
// Output GEMM -- round-3/6 structure (proven); cvt_frag now uses the fast
// cvt_pk split (W prologue 32 pairs: ~11->6 VALU each).
// Grid (64 n, 4 m, 4 b), 256 threads.
// ---------------------------------------------------------------------------
__global__ __launch_bounds__(256) void gemm2_fused(
    const float* __restrict__ wo,
    const unsigned short* __restrict__ Oth, const unsigned short* __restrict__ Otl,
    const float* __restrict__ bias, float* __restrict__ y)
{
    const int N = N_TOK;
    const int b = blockIdx.z;
    const int row0 = blockIdx.y * 64;
    const int col0 = blockIdx.x * 64;
    const int t = threadIdx.x;
    const int wave = t >> 6, lane = t & 63;
    const int l16 = lane & 15, quad = lane >> 4;
    const int msub0 = (wave & 1) * 32, nsub0 = (wave >> 1) * 32;

    __shared__ __align__(16) char smem[17408];
    unsigned short* BsH = (unsigned short*)smem;           // [64][40]
    unsigned short* BsL = (unsigned short*)(smem + 5120);  // [64][40]
    float (*LdsF)[68] = (float(*)[68])smem;                // epilogue reuse

    short8 ah[4][2], al[4][2];
#pragma unroll
    for (int kc = 0; kc < 4; ++kc)
#pragma unroll
        for (int r = 0; r < 2; ++r)
            cvt_frag(wo + (size_t)(row0 + msub0 + r * 16 + l16) * 128 +
                         kc * 32 + quad * 8,
                     ah[kc][r], al[kc][r]);

    const int srow = t >> 2, sk = (t & 3) * 8;
    const unsigned short* gH = Oth + ((size_t)b * N + col0 + srow) * 128 + sk;
    const unsigned short* gL = Otl + ((size_t)b * N + col0 + srow) * 128 + sk;

    floatx4 acc[2][2] = {};
#pragma unroll
    for (int kc = 0; kc < 4; ++kc) {
        short8 hreg = *(const short8*)(gH + kc * 32);
        short8 lreg = *(const short8*)(gL + kc * 32);
        __syncthreads();
        *(short8*)(BsH + srow * 40 + sk) = hreg;
        *(short8*)(BsL + srow * 40 + sk) = lreg;
        __syncthreads();
        short8 bh0 = *(const short8*)(BsH + (nsub0 + l16) * 40 + quad * 8);
        short8 bh1 = *(const short8*)(BsH + (nsub0 + 16 + l16) * 40 + quad * 8);
        short8 bl0 = *(const short8*)(BsL + (nsub0 + l16) * 40 + quad * 8);
        short8 bl1 = *(const short8*)(BsL + (nsub0 + 16 + l16) * 40 + quad * 8);
        acc[0][0] = __builtin_amdgcn_mfma_f32_16x16x32_bf16(ah[kc][0], bh0, acc[0][0], 0, 0, 0);
        acc[0][1] = __builtin_amdgcn_mfma_f32_16x16x32_bf16(ah[kc][0], bh1, acc[0][1], 0, 0, 0);
        acc[1][0] = __builtin_amdgcn_mfma_f32_16x16x32_bf16(ah[kc][1], bh0, acc[1][0], 0, 0, 0);
        acc[1][1] = __builtin_amdgcn_mfma_f32_16x16x32_bf16(ah[kc][1], bh1, acc[1][1], 0, 0, 0);
        acc[0][0] = __builtin_amdgcn_mfma_f32_16x16x32_bf16(ah[kc][0], bl0, acc[0][0], 0, 0, 0);
        acc[0][1] = __builtin_amdgcn_mfma_f32_16x16x32_bf16(ah[kc][0], bl1, acc[0][1], 0, 0, 0);
        acc[1][0] = __builtin_amdgcn_mfma_f32_16x16x32_bf16(ah[kc][1], bl0, acc[1][0], 0, 0, 0);
        acc[1][1] = __builtin_amdgcn_mfma_f32_16x16x32_bf16(ah[kc][1], bl1, acc[1][1], 0, 0, 0);
        acc[0][0] = __builtin_amdgcn_mfma_f32_16x16x32_bf16(al[kc][0], bh0, acc[0][0], 0, 0, 0);
        acc[0][1] = __builtin_amdgcn_mfma_f32_16x16x32_bf16(al[kc][0], bh1, acc[0][1], 0, 0, 0);
        acc[1][0] = __builtin_amdgcn_mfma_f32_16x16x32_bf16(al[kc][1], bh0, acc[1][0], 0, 0, 0);
        acc[1][1] = __builtin_amdgcn_mfma_f32_16x16x32_bf16(al[kc][1], bh1, acc[1][1], 0, 0, 0);
    }

    __syncthreads();
#pragma unroll
    for (int i = 0; i < 2; ++i)
#pragma unroll
        for (int j = 0; j < 2; ++j) {
            const int m = msub0 + i * 16 + quad * 4;
            const int n = nsub0 + j * 16 + l16;
#pragma unroll
            for (int r = 0; r < 4; ++r) LdsF[m + r][n] = acc[i][j][r];
        }
    __syncthreads();
    const int m = t >> 2, nb = (t & 3) * 16;
    const float bv = bias[row0 + m];
    float* dst = y + ((size_t)b * 256 + row0 + m) * N + col0 + nb;
#pragma unroll
    for (int g = 0; g < 4; ++g) {
        float4 o4;
        o4.x = LdsF[m][nb + g * 4 + 0] + bv;
        o4.y = LdsF[m][nb + g * 4 + 1] + bv;
        o4.z = LdsF[m][nb + g * 4 + 2] + bv;
        o4.w = LdsF[m][nb + g * 4 + 3] + bv;
        *(float4*)(dst + g * 4) = o4;
    }
}

extern "C" void kernel_launch(void* const* d_in, const int* in_sizes, int n_in,
                              void* d_out, int out_size, void* d_ws, size_t ws_size,
                              hipStream_t stream) {
    const float* x     = (const float*)d_in[0];
    const float* w_qkv = (const float*)d_in[1];
    const float* w_out = (const float*)d_in[2];
    const float* b_out = (const float*)d_in[3];
    float* y = (float*)d_out;

    // workspace 20 MiB: Qp, Kp, Vp, Oth, Otl (4 MiB each)
    char* base = (char*)d_ws;
    unsigned short* Qp  = (unsigned short*)base;
    unsigned short* Kp  = Qp + (size_t)16 * N_TOK * 32;
    unsigned short* Vp  = Kp + (size_t)16 * N_TOK * 32;
    unsigned short* Oth = Vp + (size_t)16 * N_TOK * 32;
    unsigned short* Otl = Oth + (size_t)BATCH * N_TOK * 128;

    gemm1_fused<<<dim3(64, 3, BATCH), dim3(256), 0, stream>>>(
        w_qkv, x, Qp, Kp, Vp);
    attn_fused<<<dim3(32, 16), dim3(512), 0, stream>>>(Qp, Kp, Vp, Oth, Otl);
    gemm2_fused<<<dim3(64, 4, BATCH), dim3(256), 0, stream>>>(
        w_out, Oth, Otl, b_out, y);
}